// Round 7
// baseline (87122.449 us; speedup 1.0000x reference)
//
#include <hip/hip_runtime.h>
#include <math.h>

#define L_   4
#define H_   8
#define D_   512
#define DH   64
#define DFF_ 2048
#define V_   8000
#define B_   16
#define SENC 128
#define T_   32
#define TP1  33
#define NEGV -1e9f
#define EPSV 1e-6f
#define SQRTD 22.627416997969522f   // sqrt(512)
#define XSZ  ((size_t)TP1 * B_ * D_)   // 270336 floats
#define NB   256                        // persistent blocks (1 per CU)

// ===========================================================================
// Shared helpers
// ===========================================================================
__device__ __forceinline__ float block_sum(float s) {
    __shared__ float red[4];
    #pragma unroll
    for (int off = 32; off; off >>= 1) s += __shfl_xor(s, off);
    if ((threadIdx.x & 63) == 0) red[threadIdx.x >> 6] = s;
    __syncthreads();
    float tot = red[0] + red[1] + red[2] + red[3];
    __syncthreads();
    return tot;
}

__device__ __forceinline__ float4 block_sum4(float4 s) {
    __shared__ __align__(16) float red4[4][4];
    #pragma unroll
    for (int off = 32; off; off >>= 1) {
        s.x += __shfl_xor(s.x, off);
        s.y += __shfl_xor(s.y, off);
        s.z += __shfl_xor(s.z, off);
        s.w += __shfl_xor(s.w, off);
    }
    if ((threadIdx.x & 63) == 0) *(float4*)red4[threadIdx.x >> 6] = s;
    __syncthreads();
    float4 t;
    t.x = red4[0][0] + red4[1][0] + red4[2][0] + red4[3][0];
    t.y = red4[0][1] + red4[1][1] + red4[2][1] + red4[3][1];
    t.z = red4[0][2] + red4[1][2] + red4[2][2] + red4[3][2];
    t.w = red4[0][3] + red4[1][3] + red4[2][3] + red4[3][3];
    __syncthreads();
    return t;
}

// Two-level grid barrier, storm-free:
//  arrive : thread0 of block b stores gen to PACKED flags[b] (4 lines total).
//  gather : block 0 only — 256 threads read flags[tid]; per wave that is 64
//           CONTIGUOUS u32 = 1 line (coalesced). 4 lines per poll round.
//  release: block 0 thread0 stores gen to single go word.
//  wait   : one thread per other block read-polls go (read-share, no RMW).
// R5 failed on 256 serialized RMWs to one line; R6 failed on a 65K-thread
// poll storm over 256 distinct lines. This has neither.
__device__ __forceinline__ void gsync(unsigned* flags, unsigned* go,
                                      unsigned& gen)
{
    __syncthreads();
    gen++;
    if (threadIdx.x == 0) {
        __threadfence();                 // release this block's stores
        __hip_atomic_store(&flags[blockIdx.x], gen,
                           __ATOMIC_RELAXED, __HIP_MEMORY_SCOPE_AGENT);
    }
    if (blockIdx.x == 0) {
        unsigned v;
        do {
            v = __hip_atomic_load(&flags[threadIdx.x],
                                  __ATOMIC_RELAXED, __HIP_MEMORY_SCOPE_AGENT);
            if (v < gen) __builtin_amdgcn_s_sleep(2);
        } while (v < gen);
        __syncthreads();                 // all 256 flags observed
        if (threadIdx.x == 0)
            __hip_atomic_store(go, gen,
                               __ATOMIC_RELAXED, __HIP_MEMORY_SCOPE_AGENT);
    } else if (threadIdx.x == 0) {
        unsigned v;
        do {
            v = __hip_atomic_load(go,
                                  __ATOMIC_RELAXED, __HIP_MEMORY_SCOPE_AGENT);
            if (v < gen) __builtin_amdgcn_s_sleep(2);
        } while (v < gen);
    }
    __threadfence();                     // acquire
    __syncthreads();
}

// ===========================================================================
// Phase bodies (verbatim R3 kernels, virtual blockIdx, LDS via smem param)
// ===========================================================================

// fp32 GEMM, 32x64 tile, 256 threads (2x4 micro), double-buffered LDS.
// tmode==1: KcT transpose epilogue. smem use: [0, 3264) floats.
__device__ void gemm_tile(
    const float* __restrict__ A, const float* __restrict__ W,
    const float* __restrict__ bias, float* __restrict__ C,
    int M, int N, int K, int kchunk, size_t pstride, int relu, int tmode,
    int bx, int by, int bz, float* smem)
{
    float (*As)[16][34] = (float (*)[16][34])smem;            // [2][16][34]
    float (*Bs)[16][68] = (float (*)[16][68])(smem + 1088);   // [2][16][68]
    int tid = threadIdx.x;
    int tx = tid & 15, ty = tid >> 4;
    int m0 = by * 32, n0 = bx * 64;
    int kbeg = bz * kchunk;
    int niter = kchunk >> 4;
    C += (size_t)bz * pstride;
    int am = tid >> 2, aseg = tid & 3;
    int bk = tid >> 4, bc4 = (tid & 15) * 4;
    float4 aReg = make_float4(0.f, 0.f, 0.f, 0.f), bReg;
    {
        int k0 = kbeg;
        if (tid < 128) {
            int gm = m0 + am;
            if (gm < M) aReg = *(const float4*)&A[(size_t)gm * K + k0 + aseg * 4];
        }
        bReg = *(const float4*)&W[(size_t)(k0 + bk) * N + n0 + bc4];
    }
    if (tid < 128) {
        As[0][aseg * 4 + 0][am] = aReg.x;
        As[0][aseg * 4 + 1][am] = aReg.y;
        As[0][aseg * 4 + 2][am] = aReg.z;
        As[0][aseg * 4 + 3][am] = aReg.w;
    }
    *(float4*)&Bs[0][bk][bc4] = bReg;
    __syncthreads();
    float acc[2][4] = {};
    for (int it = 0; it < niter; it++) {
        int cur = it & 1;
        if (it + 1 < niter) {
            int k0 = kbeg + (it + 1) * 16;
            if (tid < 128) {
                int gm = m0 + am;
                aReg = make_float4(0.f, 0.f, 0.f, 0.f);
                if (gm < M) aReg = *(const float4*)&A[(size_t)gm * K + k0 + aseg * 4];
            }
            bReg = *(const float4*)&W[(size_t)(k0 + bk) * N + n0 + bc4];
        }
        #pragma unroll
        for (int kk = 0; kk < 16; kk++) {
            float2 a2 = *(const float2*)&As[cur][kk][ty * 2];
            float4 b4 = *(const float4*)&Bs[cur][kk][tx * 4];
            acc[0][0] += a2.x * b4.x; acc[0][1] += a2.x * b4.y;
            acc[0][2] += a2.x * b4.z; acc[0][3] += a2.x * b4.w;
            acc[1][0] += a2.y * b4.x; acc[1][1] += a2.y * b4.y;
            acc[1][2] += a2.y * b4.z; acc[1][3] += a2.y * b4.w;
        }
        if (it + 1 < niter) {
            int nxt = 1 - cur;
            if (tid < 128) {
                As[nxt][aseg * 4 + 0][am] = aReg.x;
                As[nxt][aseg * 4 + 1][am] = aReg.y;
                As[nxt][aseg * 4 + 2][am] = aReg.z;
                As[nxt][aseg * 4 + 3][am] = aReg.w;
            }
            *(float4*)&Bs[nxt][bk][bc4] = bReg;
        }
        __syncthreads();
    }
    #pragma unroll
    for (int i = 0; i < 2; i++) {
        int gm = m0 + ty * 2 + i;
        if (gm >= M) continue;
        #pragma unroll
        for (int j = 0; j < 4; j++) {
            int gn = n0 + tx * 4 + j;
            float vv = acc[i][j];
            if (bias) vv += bias[gn];
            if (relu) vv = fmaxf(vv, 0.f);
            if (tmode == 1)
                C[(size_t)(gm >> 7) * 65536 + (size_t)gn * SENC + (gm & 127)] = vv;
            else
                C[(size_t)gm * N + gn] = vv;
        }
    }
    __syncthreads();
}

// Fused QKV: bx: sel = bx>>3 in {q,k,v}, n-tile = bx&7. N=K=512.
__device__ void qkv_tile(
    const float* __restrict__ A, const float* __restrict__ W0,
    const float* __restrict__ W1, const float* __restrict__ W2,
    float* __restrict__ Cb, int M, int bx, int by, float* smem)
{
    float (*As)[16][34] = (float (*)[16][34])smem;
    float (*Bs)[16][68] = (float (*)[16][68])(smem + 1088);
    int sel = bx >> 3;
    const float* W = (sel == 0) ? W0 : ((sel == 1) ? W1 : W2);
    float* C = Cb + (size_t)sel * XSZ;
    int tid = threadIdx.x;
    int tx = tid & 15, ty = tid >> 4;
    int m0 = by * 32, n0 = (bx & 7) * 64;
    int am = tid >> 2, aseg = tid & 3;
    int bk = tid >> 4, bc4 = (tid & 15) * 4;
    float4 aReg = make_float4(0.f, 0.f, 0.f, 0.f), bReg;
    {
        if (tid < 128) {
            int gm = m0 + am;
            if (gm < M) aReg = *(const float4*)&A[(size_t)gm * D_ + aseg * 4];
        }
        bReg = *(const float4*)&W[(size_t)bk * D_ + n0 + bc4];
    }
    if (tid < 128) {
        As[0][aseg * 4 + 0][am] = aReg.x;
        As[0][aseg * 4 + 1][am] = aReg.y;
        As[0][aseg * 4 + 2][am] = aReg.z;
        As[0][aseg * 4 + 3][am] = aReg.w;
    }
    *(float4*)&Bs[0][bk][bc4] = bReg;
    __syncthreads();
    float acc[2][4] = {};
    for (int it = 0; it < 32; it++) {
        int cur = it & 1;
        if (it + 1 < 32) {
            int k0 = (it + 1) * 16;
            if (tid < 128) {
                int gm = m0 + am;
                aReg = make_float4(0.f, 0.f, 0.f, 0.f);
                if (gm < M) aReg = *(const float4*)&A[(size_t)gm * D_ + k0 + aseg * 4];
            }
            bReg = *(const float4*)&W[(size_t)(k0 + bk) * D_ + n0 + bc4];
        }
        #pragma unroll
        for (int kk = 0; kk < 16; kk++) {
            float2 a2 = *(const float2*)&As[cur][kk][ty * 2];
            float4 b4 = *(const float4*)&Bs[cur][kk][tx * 4];
            acc[0][0] += a2.x * b4.x; acc[0][1] += a2.x * b4.y;
            acc[0][2] += a2.x * b4.z; acc[0][3] += a2.x * b4.w;
            acc[1][0] += a2.y * b4.x; acc[1][1] += a2.y * b4.y;
            acc[1][2] += a2.y * b4.z; acc[1][3] += a2.y * b4.w;
        }
        if (it + 1 < 32) {
            int nxt = 1 - cur;
            if (tid < 128) {
                As[nxt][aseg * 4 + 0][am] = aReg.x;
                As[nxt][aseg * 4 + 1][am] = aReg.y;
                As[nxt][aseg * 4 + 2][am] = aReg.z;
                As[nxt][aseg * 4 + 3][am] = aReg.w;
            }
            *(float4*)&Bs[nxt][bk][bc4] = bReg;
        }
        __syncthreads();
    }
    #pragma unroll
    for (int i = 0; i < 2; i++) {
        int gm = m0 + ty * 2 + i;
        if (gm >= M) continue;
        #pragma unroll
        for (int j = 0; j < 4; j++) {
            int gn = n0 + tx * 4 + j;
            if (sel == 1)
                C[(size_t)(gm & 15) * 16896 + (size_t)gn * TP1 + (gm >> 4)] =
                    acc[i][j];
            else
                C[(size_t)gm * D_ + gn] = acc[i][j];
        }
    }
    __syncthreads();
}

// MEGA attn: 4 rows of batch b per call. smem use: [0, 8352) floats.
__device__ void attn_tile(
    const float* __restrict__ q, const float* __restrict__ kT,
    const float* __restrict__ v, const float* __restrict__ wo,
    const float* __restrict__ KcT, const float* __restrict__ Vc,
    const float* __restrict__ cmask, const float* __restrict__ cwq,
    const float* __restrict__ cwo, float* __restrict__ x,
    const float* __restrict__ lg, const float* __restrict__ lb,
    int P, int b, int p0, float* smem)
{
    float (*xs)[D_]            = (float (*)[D_])smem;               // 4x512
    float (*arow)[D_]          = (float (*)[D_])(smem + 2048);      // 4x512
    float (*scs)[H_][SENC + 4] = (float (*)[H_][SENC + 4])(smem + 4096);
    float (*inv)[H_]           = (float (*)[H_])(smem + 8320);
    int tid = threadIdx.x;
    int c0 = tid * 2;
    #pragma unroll
    for (int g = 0; g < 4; g++) {
        float2 qv = make_float2(0.f, 0.f);
        if (p0 + g < P)
            qv = *(const float2*)&q[((size_t)(p0 + g) * B_ + b) * D_ + c0];
        *(float2*)&arow[g][c0] = qv;
    }
    __syncthreads();
    {
        int h = tid >> 5, kp = tid & 31;
        float a0 = 0.f, a1 = 0.f, a2 = 0.f, a3 = 0.f;
        if (kp < P) {
            const float* kb = kT + ((size_t)(b * 8 + h) * 64) * TP1 + kp;
            #pragma unroll 8
            for (int d = 0; d < 64; d++) {
                float kv = kb[(size_t)d * TP1];
                a0 += arow[0][h * 64 + d] * kv;
                a1 += arow[1][h * 64 + d] * kv;
                a2 += arow[2][h * 64 + d] * kv;
                a3 += arow[3][h * 64 + d] * kv;
            }
        }
        scs[0][h][kp] = a0 * 0.125f;
        scs[1][h][kp] = a1 * 0.125f;
        scs[2][h][kp] = a2 * 0.125f;
        scs[3][h][kp] = a3 * 0.125f;
    }
    __syncthreads();
    {
        int gh = tid >> 3, lane8 = tid & 7;
        int g = gh >> 3, h = gh & 7;
        float mx = -1e30f;
        for (int j = lane8; j < P; j += 8) mx = fmaxf(mx, scs[g][h][j]);
        mx = fmaxf(mx, __shfl_xor(mx, 1));
        mx = fmaxf(mx, __shfl_xor(mx, 2));
        mx = fmaxf(mx, __shfl_xor(mx, 4));
        float sum = 0.f;
        for (int j = lane8; j < P; j += 8) {
            float e = expf(scs[g][h][j] - mx);
            scs[g][h][j] = e;
            sum += e;
        }
        sum += __shfl_xor(sum, 1);
        sum += __shfl_xor(sum, 2);
        sum += __shfl_xor(sum, 4);
        if (lane8 == 0) inv[g][h] = 1.f / sum;
    }
    __syncthreads();
    {
        int h = tid >> 5;
        float o0[4] = {0.f, 0.f, 0.f, 0.f}, o1[4] = {0.f, 0.f, 0.f, 0.f};
        for (int j = 0; j < P; j++) {
            float2 vv = *(const float2*)&v[((size_t)j * B_ + b) * D_ + c0];
            #pragma unroll
            for (int g = 0; g < 4; g++) {
                float w = scs[g][h][j];
                o0[g] += w * vv.x; o1[g] += w * vv.y;
            }
        }
        #pragma unroll
        for (int g = 0; g < 4; g++) {
            arow[g][c0]     = o0[g] * inv[g][h];
            arow[g][c0 + 1] = o1[g] * inv[g][h];
        }
    }
    __syncthreads();
    {
        float v0[4], v1[4];
        #pragma unroll
        for (int g = 0; g < 4; g++) {
            float2 xv = make_float2(0.f, 0.f);
            if (p0 + g < P)
                xv = *(const float2*)&x[((size_t)(p0 + g) * B_ + b) * D_ + c0];
            v0[g] = xv.x; v1[g] = xv.y;
        }
        #pragma unroll 8
        for (int k = 0; k < D_; k++) {
            float2 wv = *(const float2*)&wo[(size_t)k * D_ + c0];
            #pragma unroll
            for (int g = 0; g < 4; g++) {
                float a = arow[g][k];
                v0[g] += a * wv.x; v1[g] += a * wv.y;
            }
        }
        float4 s1 = make_float4(v0[0] + v1[0], v0[1] + v1[1],
                                v0[2] + v1[2], v0[3] + v1[3]);
        float4 m4 = block_sum4(s1);
        float mean[4] = {m4.x * (1.f / 512.f), m4.y * (1.f / 512.f),
                         m4.z * (1.f / 512.f), m4.w * (1.f / 512.f)};
        float d0[4], d1[4];
        #pragma unroll
        for (int g = 0; g < 4; g++) {
            d0[g] = v0[g] - mean[g]; d1[g] = v1[g] - mean[g];
        }
        float4 s2 = make_float4(d0[0] * d0[0] + d1[0] * d1[0],
                                d0[1] * d0[1] + d1[1] * d1[1],
                                d0[2] * d0[2] + d1[2] * d1[2],
                                d0[3] * d0[3] + d1[3] * d1[3]);
        float4 w4 = block_sum4(s2);
        float var[4] = {w4.x * (1.f / 512.f), w4.y * (1.f / 512.f),
                        w4.z * (1.f / 512.f), w4.w * (1.f / 512.f)};
        float g0 = lg[c0], g1 = lg[c0 + 1];
        float bb0 = lb[c0], bb1 = lb[c0 + 1];
        #pragma unroll
        for (int g = 0; g < 4; g++) {
            float rs = rsqrtf(var[g] + EPSV);
            xs[g][c0]     = d0[g] * rs * g0 + bb0;
            xs[g][c0 + 1] = d1[g] * rs * g1 + bb1;
        }
    }
    __syncthreads();
    {
        float q0[4] = {0.f, 0.f, 0.f, 0.f}, q1[4] = {0.f, 0.f, 0.f, 0.f};
        #pragma unroll 8
        for (int k = 0; k < D_; k++) {
            float2 wv = *(const float2*)&cwq[(size_t)k * D_ + c0];
            #pragma unroll
            for (int g = 0; g < 4; g++) {
                float a = xs[g][k];
                q0[g] += a * wv.x; q1[g] += a * wv.y;
            }
        }
        #pragma unroll
        for (int g = 0; g < 4; g++) {
            arow[g][c0] = q0[g]; arow[g][c0 + 1] = q1[g];
        }
    }
    __syncthreads();
    #pragma unroll
    for (int i = 0; i < 4; i++) {
        int idx = tid + i * 256;
        int h = idx >> 7, s = idx & 127;
        const float* kb = KcT + ((size_t)(b * 512 + h * 64)) * SENC + s;
        float a0 = 0.f, a1 = 0.f, a2 = 0.f, a3 = 0.f;
        #pragma unroll 8
        for (int d = 0; d < 64; d++) {
            float kc = kb[(size_t)d * SENC];
            a0 += arow[0][h * 64 + d] * kc;
            a1 += arow[1][h * 64 + d] * kc;
            a2 += arow[2][h * 64 + d] * kc;
            a3 += arow[3][h * 64 + d] * kc;
        }
        float cm = cmask[b * SENC + s];
        scs[0][h][s] = a0 * 0.125f + cm;
        scs[1][h][s] = a1 * 0.125f + cm;
        scs[2][h][s] = a2 * 0.125f + cm;
        scs[3][h][s] = a3 * 0.125f + cm;
    }
    __syncthreads();
    {
        int gh = tid >> 3, lane8 = tid & 7;
        int g = gh >> 3, h = gh & 7;
        float mx = -1e30f;
        for (int s = lane8; s < SENC; s += 8) mx = fmaxf(mx, scs[g][h][s]);
        mx = fmaxf(mx, __shfl_xor(mx, 1));
        mx = fmaxf(mx, __shfl_xor(mx, 2));
        mx = fmaxf(mx, __shfl_xor(mx, 4));
        float sum = 0.f;
        for (int s = lane8; s < SENC; s += 8) {
            float e = expf(scs[g][h][s] - mx);
            scs[g][h][s] = e;
            sum += e;
        }
        sum += __shfl_xor(sum, 1);
        sum += __shfl_xor(sum, 2);
        sum += __shfl_xor(sum, 4);
        if (lane8 == 0) inv[g][h] = 1.f / sum;
    }
    __syncthreads();
    {
        int h = tid >> 5;
        float o0[4] = {0.f, 0.f, 0.f, 0.f}, o1[4] = {0.f, 0.f, 0.f, 0.f};
        for (int s = 0; s < SENC; s++) {
            float2 vv = *(const float2*)&Vc[((size_t)b * SENC + s) * D_ + c0];
            #pragma unroll
            for (int g = 0; g < 4; g++) {
                float w = scs[g][h][s];
                o0[g] += w * vv.x; o1[g] += w * vv.y;
            }
        }
        #pragma unroll
        for (int g = 0; g < 4; g++) {
            arow[g][c0]     = o0[g] * inv[g][h];
            arow[g][c0 + 1] = o1[g] * inv[g][h];
        }
    }
    __syncthreads();
    {
        float v0[4], v1[4];
        #pragma unroll
        for (int g = 0; g < 4; g++) {
            v0[g] = xs[g][c0]; v1[g] = xs[g][c0 + 1];
        }
        #pragma unroll 8
        for (int k = 0; k < D_; k++) {
            float2 wv = *(const float2*)&cwo[(size_t)k * D_ + c0];
            #pragma unroll
            for (int g = 0; g < 4; g++) {
                float a = arow[g][k];
                v0[g] += a * wv.x; v1[g] += a * wv.y;
            }
        }
        float4 s1 = make_float4(v0[0] + v1[0], v0[1] + v1[1],
                                v0[2] + v1[2], v0[3] + v1[3]);
        float4 m4 = block_sum4(s1);
        float mean[4] = {m4.x * (1.f / 512.f), m4.y * (1.f / 512.f),
                         m4.z * (1.f / 512.f), m4.w * (1.f / 512.f)};
        float d0[4], d1[4];
        #pragma unroll
        for (int g = 0; g < 4; g++) {
            d0[g] = v0[g] - mean[g]; d1[g] = v1[g] - mean[g];
        }
        float4 s2 = make_float4(d0[0] * d0[0] + d1[0] * d1[0],
                                d0[1] * d0[1] + d1[1] * d1[1],
                                d0[2] * d0[2] + d1[2] * d1[2],
                                d0[3] * d0[3] + d1[3] * d1[3]);
        float4 w4 = block_sum4(s2);
        float var[4] = {w4.x * (1.f / 512.f), w4.y * (1.f / 512.f),
                        w4.z * (1.f / 512.f), w4.w * (1.f / 512.f)};
        float g0 = lg[D_ + c0], g1 = lg[D_ + c0 + 1];
        float bb0 = lb[D_ + c0], bb1 = lb[D_ + c0 + 1];
        #pragma unroll
        for (int g = 0; g < 4; g++) {
            if (p0 + g < P) {
                float rs = rsqrtf(var[g] + EPSV);
                float* xr = x + ((size_t)(p0 + g) * B_ + b) * D_;
                xr[c0]     = d0[g] * rs * g0 + bb0;
                xr[c0 + 1] = d1[g] * rs * g1 + bb1;
            }
        }
    }
    __syncthreads();
}

__device__ void ln_row(
    float* __restrict__ x, const float* __restrict__ parts, size_t pstride,
    int nparts, const float* __restrict__ bias,
    const float* __restrict__ gam, const float* __restrict__ bet, int r)
{
    float* xr = x + (size_t)r * D_;
    int tid = threadIdx.x;
    float v0 = xr[tid];
    float v1 = xr[tid + 256];
    for (int s = 0; s < nparts; s++) {
        const float* pr = parts + (size_t)s * pstride + (size_t)r * D_;
        v0 += pr[tid];
        v1 += pr[tid + 256];
    }
    if (bias) { v0 += bias[tid]; v1 += bias[tid + 256]; }
    float mean = block_sum(v0 + v1) * (1.f / 512.f);
    float d0 = v0 - mean, d1 = v1 - mean;
    float var = block_sum(d0 * d0 + d1 * d1) * (1.f / 512.f);
    float rs = rsqrtf(var + EPSV);
    xr[tid]       = d0 * rs * gam[tid] + bet[tid];
    xr[tid + 256] = d1 * rs * gam[tid + 256] + bet[tid + 256];
}

// logits tile: 64 cols x 4 K-chunks. smem use: [0, 12288) floats.
__device__ void logits_tile(
    const float* __restrict__ x, const float* __restrict__ fcw,
    const float* __restrict__ fcb, float* __restrict__ cand_v,
    int* __restrict__ cand_i, int t, int bx, float* smem)
{
    float (*xs)[D_]      = (float (*)[D_])smem;                 // 16x512
    float (*red)[64][B_] = (float (*)[64][B_])(smem + 8192);    // 4x64x16
    int tid = threadIdx.x;
    for (int i = tid; i < B_ * D_; i += 256) {
        int b = i >> 9, d = i & 511;
        xs[b][d] = x[((size_t)t * B_ + b) * D_ + d];
    }
    __syncthreads();
    int lane = tid & 63, ks = tid >> 6;
    int col = bx * 64 + lane;
    float acc[B_] = {};
    int kb = ks * 128;
    for (int k = kb; k < kb + 128; k++) {
        float w = fcw[(size_t)k * V_ + col];
        #pragma unroll
        for (int b = 0; b < B_; b++) acc[b] += xs[b][k] * w;
    }
    #pragma unroll
    for (int b = 0; b < B_; b++) red[ks][lane][b] = acc[b];
    __syncthreads();
    if (ks == 0) {
        float bias = fcb[col];
        #pragma unroll
        for (int b = 0; b < B_; b++) {
            float val = red[0][lane][b] + red[1][lane][b]
                      + red[2][lane][b] + red[3][lane][b] + bias;
            int idx = col;
            #pragma unroll
            for (int off = 32; off; off >>= 1) {
                float ov = __shfl_down(val, off);
                int oi = __shfl_down(idx, off);
                if (ov > val || (ov == val && oi < idx)) { val = ov; idx = oi; }
            }
            if (lane == 0) {
                cand_v[(size_t)b * 125 + bx] = val;
                cand_i[(size_t)b * 125 + bx] = idx;
            }
        }
    }
    __syncthreads();
}

// embed one (p,b) row (+argmax of prev logits when p==t). smem: [0,260).
__device__ void embed_item(
    const float* __restrict__ embed, int* __restrict__ tokens,
    float* __restrict__ x, const float* __restrict__ pe,
    const float* __restrict__ cand_v, const int* __restrict__ cand_i,
    int* __restrict__ done, int t, int p, int b, float* smem)
{
    float* sv = smem;
    int* si   = (int*)(smem + 128);
    int* stok = (int*)(smem + 256);
    int tid = threadIdx.x;
    if (p == t && t > 0) {
        if (tid < 128) {
            float val = -1e30f; int idx = 0x7fffffff;
            if (tid < 125) {
                val = cand_v[(size_t)b * 125 + tid];
                idx = cand_i[(size_t)b * 125 + tid];
            }
            sv[tid] = val; si[tid] = idx;
        }
        __syncthreads();
        for (int s = 64; s; s >>= 1) {
            if (tid < s) {
                float ov = sv[tid + s]; int oi = si[tid + s];
                if (ov > sv[tid] || (ov == sv[tid] && oi < si[tid])) {
                    sv[tid] = ov; si[tid] = oi;
                }
            }
            __syncthreads();
        }
        if (tid == 0) {
            int best = si[0];
            int dn = done[b] | (best == 2 ? 1 : 0);
            done[b] = dn;
            int tk = dn ? 0 : best;
            tokens[b * TP1 + t] = tk;
            *stok = tk;
        }
        __syncthreads();
    }
    int tok = (p == t && t > 0) ? *stok : tokens[b * TP1 + p];
    const float* e = embed + (size_t)tok * D_;
    const float* pr = pe + (size_t)p * D_;
    float* xr = x + ((size_t)p * B_ + b) * D_;
    int c0 = tid * 2;
    float2 ev = *(const float2*)&e[c0];
    float2 pv = *(const float2*)&pr[c0];
    float2 o;
    o.x = ev.x * SQRTD + pv.x;
    o.y = ev.y * SQRTD + pv.y;
    *(float2*)&xr[c0] = o;
    __syncthreads();
}

// final writeout for batch b (reduce step-31 candidates). smem: [0,260).
__device__ void writeout_item(
    const int* __restrict__ tokens, const float* __restrict__ cand_v,
    const int* __restrict__ cand_i, const int* __restrict__ done,
    int* __restrict__ out, int b, float* smem)
{
    float* sv = smem;
    int* si   = (int*)(smem + 128);
    int* stok = (int*)(smem + 256);
    int tid = threadIdx.x;
    if (tid < 128) {
        float val = -1e30f; int idx = 0x7fffffff;
        if (tid < 125) {
            val = cand_v[(size_t)b * 125 + tid];
            idx = cand_i[(size_t)b * 125 + tid];
        }
        sv[tid] = val; si[tid] = idx;
    }
    __syncthreads();
    for (int s = 64; s; s >>= 1) {
        if (tid < s && tid < 128) {
            float ov = sv[tid + s]; int oi = si[tid + s];
            if (ov > sv[tid] || (ov == sv[tid] && oi < si[tid])) {
                sv[tid] = ov; si[tid] = oi;
            }
        }
        __syncthreads();
    }
    if (tid == 0) {
        int best = si[0];
        int dn = done[b] | (best == 2 ? 1 : 0);
        *stok = dn ? 0 : best;
    }
    __syncthreads();
    if (tid < T_)
        out[b * T_ + tid] = (tid == T_ - 1) ? *stok : tokens[b * TP1 + tid + 1];
    __syncthreads();
}

// ===========================================================================
// Persistent cooperative mega-kernel: whole decode in one launch.
// ===========================================================================
struct MegaParams {
    const float *enc, *pm, *embed;
    const float *wq, *wk, *wv, *wo, *cwq, *cwk, *cwv, *cwo;
    const float *w1, *b1, *w2, *b2, *ln_g, *ln_b, *fcw, *fcb;
    float *x, *qkv, *parts, *ffnh, *cand_v, *KcT, *Vc, *cmask, *pe;
    int *cand_i, *tokens, *done, *out;
    unsigned *flags, *go;
};

__global__ __launch_bounds__(256) void mega_k(MegaParams mp)
{
    __shared__ __align__(16) float smem[12288];   // 48 KB phase union
    const int bid = blockIdx.x;
    const int tid = threadIdx.x;
    unsigned gen = 0;
    const size_t KVL = (size_t)B_ * SENC * D_;

    // ---- phase 0: init tables + KcT/Vc precompute (8 GEMMs x 512 tiles)
    for (int i = bid * 256 + tid; i < TP1 * D_; i += NB * 256) {
        int p = i / D_, d = i % D_;
        float fd = (float)(2 * (d / 2)) / (float)D_;
        float ang = (float)p / powf(10000.f, fd);
        mp.pe[i] = (d & 1) ? cosf(ang) : sinf(ang);
        if (i < B_ * TP1) mp.tokens[i] = ((i % TP1) == 0) ? 1 : 0;
        if (i < B_) mp.done[i] = 0;
        if (i < B_ * SENC) mp.cmask[i] = mp.pm[i] * NEGV;
    }
    __syncthreads();
    for (int tile = bid; tile < 8 * 512; tile += NB) {
        int g = tile >> 9, sub = tile & 511;
        int l = g >> 1, kv = g & 1;
        int bx = sub & 7, by = sub >> 3;
        if (kv == 0)
            gemm_tile(mp.enc, mp.cwk + (size_t)l * D_ * D_, nullptr,
                      mp.KcT + (size_t)l * KVL, B_ * SENC, D_, D_, D_, 0, 0, 1,
                      bx, by, 0, smem);
        else
            gemm_tile(mp.enc, mp.cwv + (size_t)l * D_ * D_, nullptr,
                      mp.Vc + (size_t)l * KVL, B_ * SENC, D_, D_, D_, 0, 0, 0,
                      bx, by, 0, smem);
    }
    gsync(mp.flags, mp.go, gen);

    // ---- decode loop
    for (int t = 0; t < T_; t++) {
        int P = t + 1, M = P * B_, mt = (M + 31) >> 5;

        for (int item = bid; item < M; item += NB)
            embed_item(mp.embed, mp.tokens, mp.x, mp.pe, mp.cand_v, mp.cand_i,
                       mp.done, t, item >> 4, item & 15, smem);
        gsync(mp.flags, mp.go, gen);

        for (int l = 0; l < L_; l++) {
            const size_t lw = (size_t)l * D_ * D_;

            for (int tile = bid; tile < 24 * mt; tile += NB)
                qkv_tile(mp.x, mp.wq + lw, mp.wk + lw, mp.wv + lw, mp.qkv, M,
                         tile % 24, tile / 24, smem);
            gsync(mp.flags, mp.go, gen);

            int pt = (P + 3) >> 2;
            for (int tile = bid; tile < 16 * pt; tile += NB)
                attn_tile(mp.qkv, mp.qkv + XSZ, mp.qkv + 2 * XSZ, mp.wo + lw,
                          mp.KcT + (size_t)l * KVL, mp.Vc + (size_t)l * KVL,
                          mp.cmask, mp.cwq + lw, mp.cwo + lw, mp.x,
                          mp.ln_g + (size_t)(l * 3 + 0) * D_,
                          mp.ln_b + (size_t)(l * 3 + 0) * D_,
                          P, tile & 15, (tile >> 4) * 4, smem);
            gsync(mp.flags, mp.go, gen);

            for (int tile = bid; tile < 32 * mt; tile += NB)
                gemm_tile(mp.x, mp.w1 + (size_t)l * D_ * DFF_,
                          mp.b1 + (size_t)l * DFF_, mp.ffnh,
                          M, DFF_, D_, D_, 0, 1, 0, tile % 32, tile / 32, 0, smem);
            gsync(mp.flags, mp.go, gen);

            for (int tile = bid; tile < 8 * mt * 4; tile += NB) {
                int bx = tile % 8, rest = tile / 8;
                gemm_tile(mp.ffnh, mp.w2 + (size_t)l * DFF_ * D_, nullptr,
                          mp.parts, M, D_, DFF_, 512, XSZ, 0, 0,
                          bx, rest % mt, rest / mt, smem);
            }
            gsync(mp.flags, mp.go, gen);

            for (int r = bid; r < M; r += NB)
                ln_row(mp.x, mp.parts, XSZ, 4, mp.b2 + (size_t)l * D_,
                       mp.ln_g + (size_t)(l * 3 + 2) * D_,
                       mp.ln_b + (size_t)(l * 3 + 2) * D_, r);
            gsync(mp.flags, mp.go, gen);
        }

        for (int tile = bid; tile < V_ / 64; tile += NB)
            logits_tile(mp.x, mp.fcw, mp.fcb, mp.cand_v, mp.cand_i, t, tile, smem);
        gsync(mp.flags, mp.go, gen);
    }

    for (int b = bid; b < B_; b += NB)
        writeout_item(mp.tokens, mp.cand_v, mp.cand_i, mp.done, mp.out, b, smem);
}

__global__ void barinit_k(unsigned* flags, unsigned* go)
{
    int i = blockIdx.x * 256 + threadIdx.x;
    if (i < NB) flags[i] = 0u;
    if (i == 0) *go = 0u;
}

// ===========================================================================
// Fallback wrappers (exact R3 launch structure) in case cooperative launch
// is rejected by the runtime/graph-capture.
// ===========================================================================
__global__ __launch_bounds__(256) void gemm32_k(
    const float* A, const float* W, const float* bias, float* C,
    int M, int N, int K, int kchunk, size_t pstride, int relu, int tmode)
{
    __shared__ __align__(16) float smem[3264];
    gemm_tile(A, W, bias, C, M, N, K, kchunk, pstride, relu, tmode,
              blockIdx.x, blockIdx.y, blockIdx.z, smem);
}

__global__ __launch_bounds__(256) void gemm_qkv_k(
    const float* A, const float* W0, const float* W1, const float* W2,
    float* Cb, int M)
{
    __shared__ __align__(16) float smem[3264];
    qkv_tile(A, W0, W1, W2, Cb, M, blockIdx.x, blockIdx.y, smem);
}

__global__ __launch_bounds__(256) void attn_mega_k(
    const float* q, const float* kT, const float* v, const float* wo,
    const float* KcT, const float* Vc, const float* cmask, const float* cwq,
    const float* cwo, float* x, const float* lg, const float* lb, int P)
{
    __shared__ __align__(16) float smem[8352];
    attn_tile(q, kT, v, wo, KcT, Vc, cmask, cwq, cwo, x, lg, lb,
              P, blockIdx.x, blockIdx.y * 4, smem);
}

__global__ __launch_bounds__(256) void ln_red_k(
    float* x, const float* parts, size_t pstride, int nparts,
    const float* bias, const float* gam, const float* bet)
{
    ln_row(x, parts, pstride, nparts, bias, gam, bet, blockIdx.x);
}

__global__ __launch_bounds__(256) void logits_k(
    const float* x, const float* fcw, const float* fcb,
    float* cand_v, int* cand_i, int t)
{
    __shared__ __align__(16) float smem[12288];
    logits_tile(x, fcw, fcb, cand_v, cand_i, t, blockIdx.x, smem);
}

__global__ __launch_bounds__(256) void embed_k(
    const float* embed, int* tokens, float* x, const float* pe,
    const float* cand_v, const int* cand_i, int* done, int t)
{
    __shared__ __align__(16) float smem[264];
    embed_item(embed, tokens, x, pe, cand_v, cand_i, done, t,
               blockIdx.x, blockIdx.y, smem);
}

__global__ __launch_bounds__(256) void initpe_k(
    int* tokens, int* done, float* cmask, const float* pm, float* pe)
{
    for (int i = blockIdx.x * 256 + threadIdx.x; i < TP1 * D_;
         i += gridDim.x * 256) {
        int p = i / D_, d = i % D_;
        float fd = (float)(2 * (d / 2)) / (float)D_;
        float ang = (float)p / powf(10000.f, fd);
        pe[i] = (d & 1) ? cosf(ang) : sinf(ang);
        if (i < B_ * TP1) tokens[i] = ((i % TP1) == 0) ? 1 : 0;
        if (i < B_) done[i] = 0;
        if (i < B_ * SENC) cmask[i] = pm[i] * NEGV;
    }
}

__global__ __launch_bounds__(256) void writeout_k(
    const int* tokens, const float* cand_v, const int* cand_i,
    const int* done, int* out)
{
    __shared__ __align__(16) float smem[264];
    writeout_item(tokens, cand_v, cand_i, done, out, blockIdx.x, smem);
}

// ===========================================================================
extern "C" void kernel_launch(void* const* d_in, const int* in_sizes, int n_in,
                              void* d_out, int out_size, void* d_ws, size_t ws_size,
                              hipStream_t stream)
{
    const float* enc   = (const float*)d_in[1];
    const float* pm    = (const float*)d_in[2];
    const float* embd  = (const float*)d_in[3];
    const float* wq    = (const float*)d_in[4];
    const float* wk    = (const float*)d_in[5];
    const float* wv    = (const float*)d_in[6];
    const float* wo    = (const float*)d_in[7];
    const float* cwq   = (const float*)d_in[8];
    const float* cwk   = (const float*)d_in[9];
    const float* cwv   = (const float*)d_in[10];
    const float* cwo   = (const float*)d_in[11];
    const float* w1    = (const float*)d_in[12];
    const float* b1    = (const float*)d_in[13];
    const float* w2    = (const float*)d_in[14];
    const float* b2    = (const float*)d_in[15];
    const float* ln_g  = (const float*)d_in[16];
    const float* ln_b  = (const float*)d_in[17];
    const float* fcw   = (const float*)d_in[18];
    const float* fcb   = (const float*)d_in[19];

    float* ws = (float*)d_ws;
    size_t off = 0;
    float* x     = ws + off; off += XSZ;
    float* qkv   = ws + off; off += 3 * XSZ;
    float* parts = ws + off; off += 4 * XSZ;
    float* ffnh  = ws + off; off += (size_t)TP1 * B_ * DFF_;
    float* cand_v= ws + off; off += (size_t)B_ * 125;
    float* KcT   = ws + off; off += (size_t)L_ * B_ * SENC * D_;
    float* Vc    = ws + off; off += (size_t)L_ * B_ * SENC * D_;
    float* cmask = ws + off; off += (size_t)B_ * SENC;
    float* pe    = ws + off; off += (size_t)TP1 * D_;
    int* cand_i  = (int*)(ws + off); off += (size_t)B_ * 125;
    int* tokens  = (int*)(ws + off); off += (B_ * TP1 + 63) & ~63;
    int* done    = (int*)(ws + off); off += 64;
    unsigned* flags = (unsigned*)(ws + off); off += NB;   // packed u32[256]
    unsigned* go    = (unsigned*)(ws + off); off += 64;   // own line

    // ---- try persistent cooperative mega-kernel
    barinit_k<<<1, 256, 0, stream>>>(flags, go);
    MegaParams mp;
    mp.enc = enc;  mp.pm = pm;  mp.embed = embd;
    mp.wq = wq;    mp.wk = wk;  mp.wv = wv;  mp.wo = wo;
    mp.cwq = cwq;  mp.cwk = cwk; mp.cwv = cwv; mp.cwo = cwo;
    mp.w1 = w1;    mp.b1 = b1;  mp.w2 = w2;  mp.b2 = b2;
    mp.ln_g = ln_g; mp.ln_b = ln_b; mp.fcw = fcw; mp.fcb = fcb;
    mp.x = x;      mp.qkv = qkv; mp.parts = parts; mp.ffnh = ffnh;
    mp.cand_v = cand_v; mp.KcT = KcT; mp.Vc = Vc; mp.cmask = cmask;
    mp.pe = pe;    mp.cand_i = cand_i; mp.tokens = tokens; mp.done = done;
    mp.out = (int*)d_out; mp.flags = flags; mp.go = go;
    void* kargs[] = { (void*)&mp };
    hipError_t err = hipLaunchCooperativeKernel(
        (const void*)mega_k, dim3(NB), dim3(256), kargs, 0, stream);
    if (err == hipSuccess) return;

    // ---- fallback: R3 multi-launch path (identical numerics)
    (void)hipGetLastError();
    initpe_k<<<66, 256, 0, stream>>>(tokens, done, cmask, pm, pe);
    const size_t KVL = (size_t)B_ * SENC * D_;
    for (int l = 0; l < L_; l++) {
        gemm32_k<<<dim3(8, (B_ * SENC) / 32), 256, 0, stream>>>(
            enc, cwk + (size_t)l * D_ * D_, nullptr, KcT + l * KVL,
            B_ * SENC, D_, D_, D_, 0, 0, 1);
        gemm32_k<<<dim3(8, (B_ * SENC) / 32), 256, 0, stream>>>(
            enc, cwv + (size_t)l * D_ * D_, nullptr, Vc + l * KVL,
            B_ * SENC, D_, D_, D_, 0, 0, 0);
    }
    for (int t = 0; t < T_; t++) {
        int P = t + 1;
        int M = P * B_;
        int mt = (M + 31) / 32;
        embed_k<<<dim3(P, B_), 256, 0, stream>>>(
            embd, tokens, x, pe, cand_v, cand_i, done, t);
        for (int l = 0; l < L_; l++) {
            const size_t lw = (size_t)l * D_ * D_;
            gemm_qkv_k<<<dim3(24, mt), 256, 0, stream>>>(
                x, wq + lw, wk + lw, wv + lw, qkv, M);
            attn_mega_k<<<dim3(B_, (P + 3) / 4), 256, 0, stream>>>(
                qkv, qkv + XSZ, qkv + 2 * XSZ, wo + lw,
                KcT + l * KVL, Vc + l * KVL, cmask, cwq + lw, cwo + lw, x,
                ln_g + (size_t)(l * 3 + 0) * D_, ln_b + (size_t)(l * 3 + 0) * D_, P);
            gemm32_k<<<dim3(32, mt), 256, 0, stream>>>(
                x, w1 + (size_t)l * D_ * DFF_, b1 + (size_t)l * DFF_, ffnh,
                M, DFF_, D_, D_, 0, 1, 0);
            gemm32_k<<<dim3(8, mt, 4), 256, 0, stream>>>(
                ffnh, w2 + (size_t)l * DFF_ * D_, nullptr, parts,
                M, D_, DFF_, 512, XSZ, 0, 0);
            ln_red_k<<<M, 256, 0, stream>>>(x, parts, XSZ, 4, b2 + (size_t)l * D_,
                ln_g + (size_t)(l * 3 + 2) * D_, ln_b + (size_t)(l * 3 + 2) * D_);
        }
        logits_k<<<V_ / 64, 256, 0, stream>>>(x, fcw, fcb, cand_v, cand_i, t);
    }
    writeout_k<<<B_, 128, 0, stream>>>(tokens, cand_v, cand_i, done, (int*)d_out);
}

// Round 8
// 24611.920 us; speedup vs baseline: 3.5398x; 3.5398x over previous
//
#include <hip/hip_runtime.h>
#include <math.h>

#define L_   4
#define H_   8
#define D_   512
#define DH   64
#define DFF_ 2048
#define V_   8000
#define B_   16
#define SENC 128
#define T_   32
#define TP1  33
#define NEGV -1e9f
#define EPSV 1e-6f
#define SQRTD 22.627416997969522f   // sqrt(512)
#define XSZ  ((size_t)TP1 * B_ * D_)   // 270336 floats

// ---------------------------------------------------------------------------
// fp32 GEMM, 32x64 tile, 256 threads (2x4 micro-tile), double-buffered LDS,
// float4 global loads. Latency regime: grids are <= ~CU count, so the 32-row
// tile's shorter per-block path beats 64x64 (+2.7ms) and 32x128/128thr
// (+9.9ms) — both measured. k-range = [blockIdx.z*kchunk, +kchunk); block z
// writes C + z*pstride. tmode==1: KcT transpose epilogue.
// ---------------------------------------------------------------------------
__global__ __launch_bounds__(256) void gemm32_k(
    const float* __restrict__ A, const float* __restrict__ W,
    const float* __restrict__ bias, float* __restrict__ C,
    int M, int N, int K, int kchunk, size_t pstride, int relu, int tmode)
{
    __shared__ __align__(16) float As[2][16][34];
    __shared__ __align__(16) float Bs[2][16][68];
    int tid = threadIdx.x;
    int tx = tid & 15, ty = tid >> 4;          // tx: 4 cols, ty: 2 rows
    int m0 = blockIdx.y * 32, n0 = blockIdx.x * 64;
    int kbeg = blockIdx.z * kchunk;
    int niter = kchunk >> 4;
    C += (size_t)blockIdx.z * pstride;
    int am = tid >> 2, aseg = tid & 3;         // A loader (tid<128)
    int bk = tid >> 4, bc4 = (tid & 15) * 4;   // B loader (all 256)
    float4 aReg = make_float4(0.f, 0.f, 0.f, 0.f), bReg;
    {
        int k0 = kbeg;
        if (tid < 128) {
            int gm = m0 + am;
            if (gm < M) aReg = *(const float4*)&A[(size_t)gm * K + k0 + aseg * 4];
        }
        bReg = *(const float4*)&W[(size_t)(k0 + bk) * N + n0 + bc4];
    }
    if (tid < 128) {
        As[0][aseg * 4 + 0][am] = aReg.x;
        As[0][aseg * 4 + 1][am] = aReg.y;
        As[0][aseg * 4 + 2][am] = aReg.z;
        As[0][aseg * 4 + 3][am] = aReg.w;
    }
    *(float4*)&Bs[0][bk][bc4] = bReg;
    __syncthreads();
    float acc[2][4] = {};
    for (int it = 0; it < niter; it++) {
        int cur = it & 1;
        if (it + 1 < niter) {
            int k0 = kbeg + (it + 1) * 16;
            if (tid < 128) {
                int gm = m0 + am;
                aReg = make_float4(0.f, 0.f, 0.f, 0.f);
                if (gm < M) aReg = *(const float4*)&A[(size_t)gm * K + k0 + aseg * 4];
            }
            bReg = *(const float4*)&W[(size_t)(k0 + bk) * N + n0 + bc4];
        }
        #pragma unroll
        for (int kk = 0; kk < 16; kk++) {
            float2 a2 = *(const float2*)&As[cur][kk][ty * 2];
            float4 b4 = *(const float4*)&Bs[cur][kk][tx * 4];
            acc[0][0] += a2.x * b4.x; acc[0][1] += a2.x * b4.y;
            acc[0][2] += a2.x * b4.z; acc[0][3] += a2.x * b4.w;
            acc[1][0] += a2.y * b4.x; acc[1][1] += a2.y * b4.y;
            acc[1][2] += a2.y * b4.z; acc[1][3] += a2.y * b4.w;
        }
        if (it + 1 < niter) {
            int nxt = 1 - cur;
            if (tid < 128) {
                As[nxt][aseg * 4 + 0][am] = aReg.x;
                As[nxt][aseg * 4 + 1][am] = aReg.y;
                As[nxt][aseg * 4 + 2][am] = aReg.z;
                As[nxt][aseg * 4 + 3][am] = aReg.w;
            }
            *(float4*)&Bs[nxt][bk][bc4] = bReg;
        }
        __syncthreads();
    }
    #pragma unroll
    for (int i = 0; i < 2; i++) {
        int gm = m0 + ty * 2 + i;
        if (gm >= M) continue;
        #pragma unroll
        for (int j = 0; j < 4; j++) {
            int gn = n0 + tx * 4 + j;
            float vv = acc[i][j];
            if (bias) vv += bias[gn];
            if (relu) vv = fmaxf(vv, 0.f);
            if (tmode == 1)
                C[(size_t)(gm >> 7) * 65536 + (size_t)gn * SENC + (gm & 127)] = vv;
            else
                C[(size_t)gm * N + gn] = vv;
        }
    }
}

// ---------------------------------------------------------------------------
// Fused QKV: blockIdx.x: sel = x>>3 in {q,k,v}, n-tile = x&7. N=K=512.
// q,v row-major; k TRANSPOSED: kT[((b*8+h)*64+d)*33 + p], gm=p*16+b, gn=h*64+d.
// ---------------------------------------------------------------------------
__global__ __launch_bounds__(256) void gemm_qkv_k(
    const float* __restrict__ A, const float* __restrict__ W0,
    const float* __restrict__ W1, const float* __restrict__ W2,
    float* __restrict__ Cb, int M)
{
    __shared__ __align__(16) float As[2][16][34];
    __shared__ __align__(16) float Bs[2][16][68];
    int sel = blockIdx.x >> 3;
    const float* W = (sel == 0) ? W0 : ((sel == 1) ? W1 : W2);
    float* C = Cb + (size_t)sel * XSZ;
    int tid = threadIdx.x;
    int tx = tid & 15, ty = tid >> 4;
    int m0 = blockIdx.y * 32, n0 = (blockIdx.x & 7) * 64;
    int am = tid >> 2, aseg = tid & 3;
    int bk = tid >> 4, bc4 = (tid & 15) * 4;
    float4 aReg = make_float4(0.f, 0.f, 0.f, 0.f), bReg;
    {
        if (tid < 128) {
            int gm = m0 + am;
            if (gm < M) aReg = *(const float4*)&A[(size_t)gm * D_ + aseg * 4];
        }
        bReg = *(const float4*)&W[(size_t)bk * D_ + n0 + bc4];
    }
    if (tid < 128) {
        As[0][aseg * 4 + 0][am] = aReg.x;
        As[0][aseg * 4 + 1][am] = aReg.y;
        As[0][aseg * 4 + 2][am] = aReg.z;
        As[0][aseg * 4 + 3][am] = aReg.w;
    }
    *(float4*)&Bs[0][bk][bc4] = bReg;
    __syncthreads();
    float acc[2][4] = {};
    for (int it = 0; it < 32; it++) {
        int cur = it & 1;
        if (it + 1 < 32) {
            int k0 = (it + 1) * 16;
            if (tid < 128) {
                int gm = m0 + am;
                aReg = make_float4(0.f, 0.f, 0.f, 0.f);
                if (gm < M) aReg = *(const float4*)&A[(size_t)gm * D_ + k0 + aseg * 4];
            }
            bReg = *(const float4*)&W[(size_t)(k0 + bk) * D_ + n0 + bc4];
        }
        #pragma unroll
        for (int kk = 0; kk < 16; kk++) {
            float2 a2 = *(const float2*)&As[cur][kk][ty * 2];
            float4 b4 = *(const float4*)&Bs[cur][kk][tx * 4];
            acc[0][0] += a2.x * b4.x; acc[0][1] += a2.x * b4.y;
            acc[0][2] += a2.x * b4.z; acc[0][3] += a2.x * b4.w;
            acc[1][0] += a2.y * b4.x; acc[1][1] += a2.y * b4.y;
            acc[1][2] += a2.y * b4.z; acc[1][3] += a2.y * b4.w;
        }
        if (it + 1 < 32) {
            int nxt = 1 - cur;
            if (tid < 128) {
                As[nxt][aseg * 4 + 0][am] = aReg.x;
                As[nxt][aseg * 4 + 1][am] = aReg.y;
                As[nxt][aseg * 4 + 2][am] = aReg.z;
                As[nxt][aseg * 4 + 3][am] = aReg.w;
            }
            *(float4*)&Bs[nxt][bk][bc4] = bReg;
        }
        __syncthreads();
    }
    #pragma unroll
    for (int i = 0; i < 2; i++) {
        int gm = m0 + ty * 2 + i;
        if (gm >= M) continue;
        #pragma unroll
        for (int j = 0; j < 4; j++) {
            int gn = n0 + tx * 4 + j;
            if (sel == 1)
                C[(size_t)(gm & 15) * 16896 + (size_t)gn * TP1 + (gm >> 4)] =
                    acc[i][j];
            else
                C[(size_t)gm * D_ + gn] = acc[i][j];
        }
    }
}

// ---------------------------------------------------------------------------
__global__ void init_k(int* __restrict__ tokens, int* __restrict__ done,
                       float* __restrict__ cmask, const float* __restrict__ pm)
{
    int tid = threadIdx.x + blockIdx.x * 256;
    if (tid < B_ * TP1) tokens[tid] = ((tid % TP1) == 0) ? 1 : 0;
    if (tid < B_) done[tid] = 0;
    if (tid < B_ * SENC) cmask[tid] = pm[tid] * NEGV;
}

// ---------------------------------------------------------------------------
// Sinusoid table, computed once: pe[p*D_+d].
// ---------------------------------------------------------------------------
__global__ __launch_bounds__(256) void pe_k(float* __restrict__ pe)
{
    int p = blockIdx.x;
    for (int d = threadIdx.x; d < D_; d += 256) {
        float fd = (float)(2 * (d / 2)) / (float)D_;
        float ang = (float)p / powf(10000.f, fd);
        pe[(size_t)p * D_ + d] = (d & 1) ? cosf(ang) : sinf(ang);
    }
}

// ---------------------------------------------------------------------------
// Fused embed + (for the p==t block) argmax of previous step's logits.
// Token update is done by exactly one block per batch (p==t), so no races.
// ---------------------------------------------------------------------------
__global__ __launch_bounds__(256) void embed_k(
    const float* __restrict__ embed, int* __restrict__ tokens,
    float* __restrict__ x, const float* __restrict__ pe,
    const float* __restrict__ cand_v, const int* __restrict__ cand_i,
    int* __restrict__ done, int t)
{
    int p = blockIdx.x;
    int b = blockIdx.y;
    int tid = threadIdx.x;
    __shared__ float sv[128];
    __shared__ int si[128];
    __shared__ int stok;
    if (p == t && t > 0) {
        if (tid < 128) {
            float val = -1e30f; int idx = 0x7fffffff;
            if (tid < 125) {
                val = cand_v[(size_t)b * 125 + tid];
                idx = cand_i[(size_t)b * 125 + tid];
            }
            sv[tid] = val; si[tid] = idx;
        }
        __syncthreads();
        for (int s = 64; s; s >>= 1) {
            if (tid < s) {
                float ov = sv[tid + s]; int oi = si[tid + s];
                if (ov > sv[tid] || (ov == sv[tid] && oi < si[tid])) {
                    sv[tid] = ov; si[tid] = oi;
                }
            }
            __syncthreads();
        }
        if (tid == 0) {
            int best = si[0];
            int dn = done[b] | (best == 2 ? 1 : 0);
            done[b] = dn;
            int tk = dn ? 0 : best;
            tokens[b * TP1 + t] = tk;
            stok = tk;
        }
        __syncthreads();
    }
    int tok = (p == t && t > 0) ? stok : tokens[b * TP1 + p];
    const float* e = embed + (size_t)tok * D_;
    const float* pr = pe + (size_t)p * D_;
    float* xr = x + ((size_t)p * B_ + b) * D_;
    int c0 = tid * 2;
    float2 ev = *(const float2*)&e[c0];
    float2 pv = *(const float2*)&pr[c0];
    float2 o;
    o.x = ev.x * SQRTD + pv.x;
    o.y = ev.y * SQRTD + pv.y;
    *(float2*)&xr[c0] = o;
}

// ---------------------------------------------------------------------------
__device__ __forceinline__ float block_sum(float s) {
    __shared__ float red[4];
    #pragma unroll
    for (int off = 32; off; off >>= 1) s += __shfl_xor(s, off);
    if ((threadIdx.x & 63) == 0) red[threadIdx.x >> 6] = s;
    __syncthreads();
    float tot = red[0] + red[1] + red[2] + red[3];
    __syncthreads();
    return tot;
}

// 4 independent block-wide sums (one per row-of-4-group) in one pass.
__device__ __forceinline__ float4 block_sum4(float4 s) {
    __shared__ __align__(16) float red4[4][4];
    #pragma unroll
    for (int off = 32; off; off >>= 1) {
        s.x += __shfl_xor(s.x, off);
        s.y += __shfl_xor(s.y, off);
        s.z += __shfl_xor(s.z, off);
        s.w += __shfl_xor(s.w, off);
    }
    if ((threadIdx.x & 63) == 0) *(float4*)red4[threadIdx.x >> 6] = s;
    __syncthreads();
    float4 t;
    t.x = red4[0][0] + red4[1][0] + red4[2][0] + red4[3][0];
    t.y = red4[0][1] + red4[1][1] + red4[2][1] + red4[3][1];
    t.z = red4[0][2] + red4[1][2] + red4[2][2] + red4[3][2];
    t.w = red4[0][3] + red4[1][3] + red4[2][3] + red4[3][3];
    __syncthreads();
    return t;
}

// ---------------------------------------------------------------------------
// MEGA: self-attn + wo + LN + cross(q-proj, attn, cwo) + LN.
// G=4 rows of the SAME batch per block: grid (B_, ceil(P/4)); rows
// r_g = (p0+g)*B + b. Amortizes wo/cwq/cwo (3 MB) and v/Vc/KcT reads 4x.
// Weight loops stay ROW-MAJOR float2 (wave-coalesced 2KB segments) —
// transposed per-lane streams measured +8ms (uncoalesced).
// ---------------------------------------------------------------------------
__global__ __launch_bounds__(256) void attn_mega_k(
    const float* __restrict__ q, const float* __restrict__ kT,
    const float* __restrict__ v, const float* __restrict__ wo,
    const float* __restrict__ KcT, const float* __restrict__ Vc,
    const float* __restrict__ cmask, const float* __restrict__ cwq,
    const float* __restrict__ cwo, float* __restrict__ x,
    const float* __restrict__ lg, const float* __restrict__ lb, int P)
{
    int b = blockIdx.x;
    int p0 = blockIdx.y * 4;
    int tid = threadIdx.x;
    int c0 = tid * 2;
    __shared__ float xs[4][D_];
    __shared__ float arow[4][D_];
    __shared__ float scs[4][H_][SENC + 4];
    __shared__ float inv[4][H_];
    // ---- stage q rows into arow (invalid rows -> 0)
    #pragma unroll
    for (int g = 0; g < 4; g++) {
        float2 qv = make_float2(0.f, 0.f);
        if (p0 + g < P)
            qv = *(const float2*)&q[((size_t)(p0 + g) * B_ + b) * D_ + c0];
        *(float2*)&arow[g][c0] = qv;
    }
    __syncthreads();
    // ---- self scores: thread (h=tid>>5, kp=tid&31), 4 rows per thread
    {
        int h = tid >> 5, kp = tid & 31;
        float a0 = 0.f, a1 = 0.f, a2 = 0.f, a3 = 0.f;
        if (kp < P) {
            const float* kb = kT + ((size_t)(b * 8 + h) * 64) * TP1 + kp;
            #pragma unroll 8
            for (int d = 0; d < 64; d++) {
                float kv = kb[(size_t)d * TP1];
                a0 += arow[0][h * 64 + d] * kv;
                a1 += arow[1][h * 64 + d] * kv;
                a2 += arow[2][h * 64 + d] * kv;
                a3 += arow[3][h * 64 + d] * kv;
            }
        }
        scs[0][h][kp] = a0 * 0.125f;
        scs[1][h][kp] = a1 * 0.125f;
        scs[2][h][kp] = a2 * 0.125f;
        scs[3][h][kp] = a3 * 0.125f;
    }
    __syncthreads();
    // ---- self softmax: 32 (g,h) groups x 8 lanes, shuffle reduce
    {
        int gh = tid >> 3, lane8 = tid & 7;
        int g = gh >> 3, h = gh & 7;
        float mx = -1e30f;
        for (int j = lane8; j < P; j += 8) mx = fmaxf(mx, scs[g][h][j]);
        mx = fmaxf(mx, __shfl_xor(mx, 1));
        mx = fmaxf(mx, __shfl_xor(mx, 2));
        mx = fmaxf(mx, __shfl_xor(mx, 4));
        float sum = 0.f;
        for (int j = lane8; j < P; j += 8) {
            float e = expf(scs[g][h][j] - mx);
            scs[g][h][j] = e;
            sum += e;
        }
        sum += __shfl_xor(sum, 1);
        sum += __shfl_xor(sum, 2);
        sum += __shfl_xor(sum, 4);
        if (lane8 == 0) inv[g][h] = 1.f / sum;
    }
    __syncthreads();
    // ---- self weighted V -> arow (v row shared by all 4 g: same batch b)
    {
        int h = tid >> 5;
        float o0[4] = {0.f, 0.f, 0.f, 0.f}, o1[4] = {0.f, 0.f, 0.f, 0.f};
        for (int j = 0; j < P; j++) {
            float2 vv = *(const float2*)&v[((size_t)j * B_ + b) * D_ + c0];
            #pragma unroll
            for (int g = 0; g < 4; g++) {
                float w = scs[g][h][j];
                o0[g] += w * vv.x; o1[g] += w * vv.y;
            }
        }
        #pragma unroll
        for (int g = 0; g < 4; g++) {
            arow[g][c0]     = o0[g] * inv[g][h];
            arow[g][c0 + 1] = o1[g] * inv[g][h];
        }
    }
    __syncthreads();
    // ---- wo out-proj + residual + LN -> xs (8 FMA per 8B weight read)
    {
        float v0[4], v1[4];
        #pragma unroll
        for (int g = 0; g < 4; g++) {
            float2 xv = make_float2(0.f, 0.f);
            if (p0 + g < P)
                xv = *(const float2*)&x[((size_t)(p0 + g) * B_ + b) * D_ + c0];
            v0[g] = xv.x; v1[g] = xv.y;
        }
        #pragma unroll 8
        for (int k = 0; k < D_; k++) {
            float2 wv = *(const float2*)&wo[(size_t)k * D_ + c0];
            #pragma unroll
            for (int g = 0; g < 4; g++) {
                float a = arow[g][k];
                v0[g] += a * wv.x; v1[g] += a * wv.y;
            }
        }
        float4 s1 = make_float4(v0[0] + v1[0], v0[1] + v1[1],
                                v0[2] + v1[2], v0[3] + v1[3]);
        float4 m4 = block_sum4(s1);
        float mean[4] = {m4.x * (1.f / 512.f), m4.y * (1.f / 512.f),
                         m4.z * (1.f / 512.f), m4.w * (1.f / 512.f)};
        float d0[4], d1[4];
        #pragma unroll
        for (int g = 0; g < 4; g++) {
            d0[g] = v0[g] - mean[g]; d1[g] = v1[g] - mean[g];
        }
        float4 s2 = make_float4(d0[0] * d0[0] + d1[0] * d1[0],
                                d0[1] * d0[1] + d1[1] * d1[1],
                                d0[2] * d0[2] + d1[2] * d1[2],
                                d0[3] * d0[3] + d1[3] * d1[3]);
        float4 w4 = block_sum4(s2);
        float var[4] = {w4.x * (1.f / 512.f), w4.y * (1.f / 512.f),
                        w4.z * (1.f / 512.f), w4.w * (1.f / 512.f)};
        float g0 = lg[c0], g1 = lg[c0 + 1];
        float bb0 = lb[c0], bb1 = lb[c0 + 1];
        #pragma unroll
        for (int g = 0; g < 4; g++) {
            float rs = rsqrtf(var[g] + EPSV);
            xs[g][c0]     = d0[g] * rs * g0 + bb0;
            xs[g][c0 + 1] = d1[g] * rs * g1 + bb1;
        }
    }
    __syncthreads();
    // ---- cross q-proj -> arow
    {
        float q0[4] = {0.f, 0.f, 0.f, 0.f}, q1[4] = {0.f, 0.f, 0.f, 0.f};
        #pragma unroll 8
        for (int k = 0; k < D_; k++) {
            float2 wv = *(const float2*)&cwq[(size_t)k * D_ + c0];
            #pragma unroll
            for (int g = 0; g < 4; g++) {
                float a = xs[g][k];
                q0[g] += a * wv.x; q1[g] += a * wv.y;
            }
        }
        #pragma unroll
        for (int g = 0; g < 4; g++) {
            arow[g][c0] = q0[g]; arow[g][c0 + 1] = q1[g];
        }
    }
    __syncthreads();
    // ---- cross scores: 4 (h,s) pairs per thread, 4 rows each
    #pragma unroll
    for (int i = 0; i < 4; i++) {
        int idx = tid + i * 256;
        int h = idx >> 7, s = idx & 127;
        const float* kb = KcT + ((size_t)(b * 512 + h * 64)) * SENC + s;
        float a0 = 0.f, a1 = 0.f, a2 = 0.f, a3 = 0.f;
        #pragma unroll 8
        for (int d = 0; d < 64; d++) {
            float kc = kb[(size_t)d * SENC];
            a0 += arow[0][h * 64 + d] * kc;
            a1 += arow[1][h * 64 + d] * kc;
            a2 += arow[2][h * 64 + d] * kc;
            a3 += arow[3][h * 64 + d] * kc;
        }
        float cm = cmask[b * SENC + s];
        scs[0][h][s] = a0 * 0.125f + cm;
        scs[1][h][s] = a1 * 0.125f + cm;
        scs[2][h][s] = a2 * 0.125f + cm;
        scs[3][h][s] = a3 * 0.125f + cm;
    }
    __syncthreads();
    // ---- cross softmax
    {
        int gh = tid >> 3, lane8 = tid & 7;
        int g = gh >> 3, h = gh & 7;
        float mx = -1e30f;
        for (int s = lane8; s < SENC; s += 8) mx = fmaxf(mx, scs[g][h][s]);
        mx = fmaxf(mx, __shfl_xor(mx, 1));
        mx = fmaxf(mx, __shfl_xor(mx, 2));
        mx = fmaxf(mx, __shfl_xor(mx, 4));
        float sum = 0.f;
        for (int s = lane8; s < SENC; s += 8) {
            float e = expf(scs[g][h][s] - mx);
            scs[g][h][s] = e;
            sum += e;
        }
        sum += __shfl_xor(sum, 1);
        sum += __shfl_xor(sum, 2);
        sum += __shfl_xor(sum, 4);
        if (lane8 == 0) inv[g][h] = 1.f / sum;
    }
    __syncthreads();
    // ---- cross weighted V -> arow (Vc rows shared across g)
    {
        int h = tid >> 5;
        float o0[4] = {0.f, 0.f, 0.f, 0.f}, o1[4] = {0.f, 0.f, 0.f, 0.f};
        for (int s = 0; s < SENC; s++) {
            float2 vv = *(const float2*)&Vc[((size_t)b * SENC + s) * D_ + c0];
            #pragma unroll
            for (int g = 0; g < 4; g++) {
                float w = scs[g][h][s];
                o0[g] += w * vv.x; o1[g] += w * vv.y;
            }
        }
        #pragma unroll
        for (int g = 0; g < 4; g++) {
            arow[g][c0]     = o0[g] * inv[g][h];
            arow[g][c0 + 1] = o1[g] * inv[g][h];
        }
    }
    __syncthreads();
    // ---- cwo out-proj + residual(xs) + LN -> x (guarded stores)
    {
        float v0[4], v1[4];
        #pragma unroll
        for (int g = 0; g < 4; g++) {
            v0[g] = xs[g][c0]; v1[g] = xs[g][c0 + 1];
        }
        #pragma unroll 8
        for (int k = 0; k < D_; k++) {
            float2 wv = *(const float2*)&cwo[(size_t)k * D_ + c0];
            #pragma unroll
            for (int g = 0; g < 4; g++) {
                float a = arow[g][k];
                v0[g] += a * wv.x; v1[g] += a * wv.y;
            }
        }
        float4 s1 = make_float4(v0[0] + v1[0], v0[1] + v1[1],
                                v0[2] + v1[2], v0[3] + v1[3]);
        float4 m4 = block_sum4(s1);
        float mean[4] = {m4.x * (1.f / 512.f), m4.y * (1.f / 512.f),
                         m4.z * (1.f / 512.f), m4.w * (1.f / 512.f)};
        float d0[4], d1[4];
        #pragma unroll
        for (int g = 0; g < 4; g++) {
            d0[g] = v0[g] - mean[g]; d1[g] = v1[g] - mean[g];
        }
        float4 s2 = make_float4(d0[0] * d0[0] + d1[0] * d1[0],
                                d0[1] * d0[1] + d1[1] * d1[1],
                                d0[2] * d0[2] + d1[2] * d1[2],
                                d0[3] * d0[3] + d1[3] * d1[3]);
        float4 w4 = block_sum4(s2);
        float var[4] = {w4.x * (1.f / 512.f), w4.y * (1.f / 512.f),
                        w4.z * (1.f / 512.f), w4.w * (1.f / 512.f)};
        float g0 = lg[D_ + c0], g1 = lg[D_ + c0 + 1];
        float bb0 = lb[D_ + c0], bb1 = lb[D_ + c0 + 1];
        #pragma unroll
        for (int g = 0; g < 4; g++) {
            if (p0 + g < P) {
                float rs = rsqrtf(var[g] + EPSV);
                float* xr = x + ((size_t)(p0 + g) * B_ + b) * D_;
                xr[c0]     = d0[g] * rs * g0 + bb0;
                xr[c0 + 1] = d1[g] * rs * g1 + bb1;
            }
        }
    }
}

// ---------------------------------------------------------------------------
// x = LN(x + sum_parts (+ bias)) * g + b. One block per row.
// ---------------------------------------------------------------------------
__global__ __launch_bounds__(256) void ln_red_k(
    float* __restrict__ x, const float* __restrict__ parts, size_t pstride,
    int nparts, const float* __restrict__ bias,
    const float* __restrict__ gam, const float* __restrict__ bet)
{
    int r = blockIdx.x;
    float* xr = x + (size_t)r * D_;
    int tid = threadIdx.x;
    float v0 = xr[tid];
    float v1 = xr[tid + 256];
    for (int s = 0; s < nparts; s++) {
        const float* pr = parts + (size_t)s * pstride + (size_t)r * D_;
        v0 += pr[tid];
        v1 += pr[tid + 256];
    }
    if (bias) { v0 += bias[tid]; v1 += bias[tid + 256]; }
    float mean = block_sum(v0 + v1) * (1.f / 512.f);
    float d0 = v0 - mean, d1 = v1 - mean;
    float var = block_sum(d0 * d0 + d1 * d1) * (1.f / 512.f);
    float rs = rsqrtf(var + EPSV);
    xr[tid]       = d0 * rs * gam[tid] + bet[tid];
    xr[tid + 256] = d1 * rs * gam[tid + 256] + bet[tid + 256];
}

// ---------------------------------------------------------------------------
// logits -> per-block argmax candidates. Grid 125 x 256 thr = 64 cols x
// 4 K-chunks. x row reads are lane-uniform -> scalar-cache loads, no LDS
// staging (the old xs broadcast was ~2048 ds_reads/thread). Verified correct
// in R4 (passed); summation order identical.
// ---------------------------------------------------------------------------
__global__ __launch_bounds__(256) void logits_k(
    const float* __restrict__ x, const float* __restrict__ fcw,
    const float* __restrict__ fcb, float* __restrict__ cand_v,
    int* __restrict__ cand_i, int t)
{
    __shared__ float red[4][64][B_];
    int tid = threadIdx.x;
    int lane = tid & 63, ks = tid >> 6;
    int col = blockIdx.x * 64 + lane;
    const float* xr = x + (size_t)t * B_ * D_;
    float acc[B_] = {};
    int kb = ks * 128;
    for (int k = kb; k < kb + 128; k++) {
        float w = fcw[(size_t)k * V_ + col];
        #pragma unroll
        for (int b = 0; b < B_; b++) acc[b] += xr[(size_t)b * D_ + k] * w;
    }
    #pragma unroll
    for (int b = 0; b < B_; b++) red[ks][lane][b] = acc[b];
    __syncthreads();
    if (ks == 0) {      // wave 0 only
        float bias = fcb[col];
        #pragma unroll
        for (int b = 0; b < B_; b++) {
            float val = red[0][lane][b] + red[1][lane][b]
                      + red[2][lane][b] + red[3][lane][b] + bias;
            int idx = col;
            #pragma unroll
            for (int off = 32; off; off >>= 1) {
                float ov = __shfl_down(val, off);
                int oi = __shfl_down(idx, off);
                if (ov > val || (ov == val && oi < idx)) { val = ov; idx = oi; }
            }
            if (lane == 0) {
                cand_v[(size_t)b * 125 + blockIdx.x] = val;
                cand_i[(size_t)b * 125 + blockIdx.x] = idx;
            }
        }
    }
}

// ---------------------------------------------------------------------------
// Final: one block per batch. Reduce step-31 candidates for token 32, copy
// the output row.
// ---------------------------------------------------------------------------
__global__ __launch_bounds__(128) void writeout_k(
    const int* __restrict__ tokens, const float* __restrict__ cand_v,
    const int* __restrict__ cand_i, const int* __restrict__ done,
    int* __restrict__ out)
{
    int b = blockIdx.x;
    int tid = threadIdx.x;
    __shared__ float sv[128];
    __shared__ int si[128];
    __shared__ int stok;
    float val = -1e30f; int idx = 0x7fffffff;
    if (tid < 125) {
        val = cand_v[(size_t)b * 125 + tid];
        idx = cand_i[(size_t)b * 125 + tid];
    }
    sv[tid] = val; si[tid] = idx;
    __syncthreads();
    for (int s = 64; s; s >>= 1) {
        if (tid < s) {
            float ov = sv[tid + s]; int oi = si[tid + s];
            if (ov > sv[tid] || (ov == sv[tid] && oi < si[tid])) {
                sv[tid] = ov; si[tid] = oi;
            }
        }
        __syncthreads();
    }
    if (tid == 0) {
        int best = si[0];
        int dn = done[b] | (best == 2 ? 1 : 0);
        stok = dn ? 0 : best;
    }
    __syncthreads();
    if (tid < T_)
        out[b * T_ + tid] = (tid == T_ - 1) ? stok : tokens[b * TP1 + tid + 1];
}

// ---------------------------------------------------------------------------
extern "C" void kernel_launch(void* const* d_in, const int* in_sizes, int n_in,
                              void* d_out, int out_size, void* d_ws, size_t ws_size,
                              hipStream_t stream)
{
    const float* enc   = (const float*)d_in[1];
    const float* pm    = (const float*)d_in[2];
    const float* embed = (const float*)d_in[3];
    const float* wq    = (const float*)d_in[4];
    const float* wk    = (const float*)d_in[5];
    const float* wv    = (const float*)d_in[6];
    const float* wo    = (const float*)d_in[7];
    const float* cwq   = (const float*)d_in[8];
    const float* cwk   = (const float*)d_in[9];
    const float* cwv   = (const float*)d_in[10];
    const float* cwo   = (const float*)d_in[11];
    const float* w1    = (const float*)d_in[12];
    const float* b1    = (const float*)d_in[13];
    const float* w2    = (const float*)d_in[14];
    const float* b2    = (const float*)d_in[15];
    const float* ln_g  = (const float*)d_in[16];
    const float* ln_b  = (const float*)d_in[17];
    const float* fcw   = (const float*)d_in[18];
    const float* fcb   = (const float*)d_in[19];

    float* ws = (float*)d_ws;
    size_t off = 0;
    float* x     = ws + off; off += XSZ;
    float* qkv   = ws + off; off += 3 * XSZ;      // q | kT | v
    float* parts = ws + off; off += 4 * XSZ;      // split-K partials
    float* ffnh  = ws + off; off += (size_t)TP1 * B_ * DFF_;
    float* cand_v= ws + off; off += (size_t)B_ * 125;
    float* KcT   = ws + off; off += (size_t)L_ * B_ * SENC * D_;
    float* Vc    = ws + off; off += (size_t)L_ * B_ * SENC * D_;
    float* cmask = ws + off; off += (size_t)B_ * SENC;
    float* pe    = ws + off; off += (size_t)TP1 * D_;
    int* cand_i  = (int*)(ws + off); off += (size_t)B_ * 125;
    int* tokens  = (int*)(ws + off); off += (B_ * TP1 + 63) & ~63;
    int* done    = (int*)(ws + off); off += 64;

    init_k<<<8, 256, 0, stream>>>(tokens, done, cmask, pm);
    pe_k<<<TP1, 256, 0, stream>>>(pe);

    // Precompute cross K (transposed) / V per layer
    const size_t KVL = (size_t)B_ * SENC * D_;
    for (int l = 0; l < L_; l++) {
        gemm32_k<<<dim3(8, (B_ * SENC) / 32), 256, 0, stream>>>(
            enc, cwk + (size_t)l * D_ * D_, nullptr, KcT + l * KVL,
            B_ * SENC, D_, D_, D_, 0, 0, 1);
        gemm32_k<<<dim3(8, (B_ * SENC) / 32), 256, 0, stream>>>(
            enc, cwv + (size_t)l * D_ * D_, nullptr, Vc + l * KVL,
            B_ * SENC, D_, D_, D_, 0, 0, 0);
    }

    for (int t = 0; t < T_; t++) {
        int P = t + 1;
        int M = P * B_;
        int mt = (M + 31) / 32;

        embed_k<<<dim3(P, B_), 256, 0, stream>>>(
            embed, tokens, x, pe, cand_v, cand_i, done, t);

        for (int l = 0; l < L_; l++) {
            const size_t lw = (size_t)l * D_ * D_;
            gemm_qkv_k<<<dim3(24, mt), 256, 0, stream>>>(
                x, wq + lw, wk + lw, wv + lw, qkv, M);
            attn_mega_k<<<dim3(B_, (P + 3) / 4), 256, 0, stream>>>(
                qkv, qkv + XSZ, qkv + 2 * XSZ, wo + lw,
                KcT + l * KVL, Vc + l * KVL, cmask, cwq + lw, cwo + lw, x,
                ln_g + (size_t)(l * 3 + 0) * D_, ln_b + (size_t)(l * 3 + 0) * D_, P);
            gemm32_k<<<dim3(32, mt), 256, 0, stream>>>(
                x, w1 + (size_t)l * D_ * DFF_, b1 + (size_t)l * DFF_, ffnh,
                M, DFF_, D_, D_, 0, 1, 0);
            gemm32_k<<<dim3(8, mt, 4), 256, 0, stream>>>(
                ffnh, w2 + (size_t)l * DFF_ * D_, nullptr, parts,
                M, D_, DFF_, 512, XSZ, 0, 0);
            ln_red_k<<<M, 256, 0, stream>>>(x, parts, XSZ, 4, b2 + (size_t)l * D_,
                ln_g + (size_t)(l * 3 + 2) * D_, ln_b + (size_t)(l * 3 + 2) * D_);
        }

        logits_k<<<V_ / 64, 256, 0, stream>>>(x, fcw, fcb, cand_v, cand_i, t);
    }

    writeout_k<<<B_, 128, 0, stream>>>(tokens, cand_v, cand_i, done, (int*)d_out);
}

// Round 9
// 23603.642 us; speedup vs baseline: 3.6911x; 1.0427x over previous
//
#include <hip/hip_runtime.h>
#include <math.h>

#define L_   4
#define H_   8
#define D_   512
#define DH   64
#define DFF_ 2048
#define V_   8000
#define B_   16
#define SENC 128
#define T_   32
#define TP1  33
#define NEGV -1e9f
#define EPSV 1e-6f
#define SQRTD 22.627416997969522f   // sqrt(512)
#define XSZ  ((size_t)TP1 * B_ * D_)   // 270336 floats
#define NCH  16                         // dff chunks (2048/128)

// ---------------------------------------------------------------------------
// fp32 GEMM, 32x64 tile, 256 threads (2x4 micro-tile), double-buffered LDS,
// float4 global loads. Latency regime: 32-row tile's short per-block path
// beats 64x64 (+2.7ms) and 32x128/128thr (+9.9ms) — both measured.
// tmode==1: KcT transpose epilogue.
// ---------------------------------------------------------------------------
__global__ __launch_bounds__(256) void gemm32_k(
    const float* __restrict__ A, const float* __restrict__ W,
    const float* __restrict__ bias, float* __restrict__ C,
    int M, int N, int K, int kchunk, size_t pstride, int relu, int tmode)
{
    __shared__ __align__(16) float As[2][16][34];
    __shared__ __align__(16) float Bs[2][16][68];
    int tid = threadIdx.x;
    int tx = tid & 15, ty = tid >> 4;
    int m0 = blockIdx.y * 32, n0 = blockIdx.x * 64;
    int kbeg = blockIdx.z * kchunk;
    int niter = kchunk >> 4;
    C += (size_t)blockIdx.z * pstride;
    int am = tid >> 2, aseg = tid & 3;
    int bk = tid >> 4, bc4 = (tid & 15) * 4;
    float4 aReg = make_float4(0.f, 0.f, 0.f, 0.f), bReg;
    {
        int k0 = kbeg;
        if (tid < 128) {
            int gm = m0 + am;
            if (gm < M) aReg = *(const float4*)&A[(size_t)gm * K + k0 + aseg * 4];
        }
        bReg = *(const float4*)&W[(size_t)(k0 + bk) * N + n0 + bc4];
    }
    if (tid < 128) {
        As[0][aseg * 4 + 0][am] = aReg.x;
        As[0][aseg * 4 + 1][am] = aReg.y;
        As[0][aseg * 4 + 2][am] = aReg.z;
        As[0][aseg * 4 + 3][am] = aReg.w;
    }
    *(float4*)&Bs[0][bk][bc4] = bReg;
    __syncthreads();
    float acc[2][4] = {};
    for (int it = 0; it < niter; it++) {
        int cur = it & 1;
        if (it + 1 < niter) {
            int k0 = kbeg + (it + 1) * 16;
            if (tid < 128) {
                int gm = m0 + am;
                aReg = make_float4(0.f, 0.f, 0.f, 0.f);
                if (gm < M) aReg = *(const float4*)&A[(size_t)gm * K + k0 + aseg * 4];
            }
            bReg = *(const float4*)&W[(size_t)(k0 + bk) * N + n0 + bc4];
        }
        #pragma unroll
        for (int kk = 0; kk < 16; kk++) {
            float2 a2 = *(const float2*)&As[cur][kk][ty * 2];
            float4 b4 = *(const float4*)&Bs[cur][kk][tx * 4];
            acc[0][0] += a2.x * b4.x; acc[0][1] += a2.x * b4.y;
            acc[0][2] += a2.x * b4.z; acc[0][3] += a2.x * b4.w;
            acc[1][0] += a2.y * b4.x; acc[1][1] += a2.y * b4.y;
            acc[1][2] += a2.y * b4.z; acc[1][3] += a2.y * b4.w;
        }
        if (it + 1 < niter) {
            int nxt = 1 - cur;
            if (tid < 128) {
                As[nxt][aseg * 4 + 0][am] = aReg.x;
                As[nxt][aseg * 4 + 1][am] = aReg.y;
                As[nxt][aseg * 4 + 2][am] = aReg.z;
                As[nxt][aseg * 4 + 3][am] = aReg.w;
            }
            *(float4*)&Bs[nxt][bk][bc4] = bReg;
        }
        __syncthreads();
    }
    #pragma unroll
    for (int i = 0; i < 2; i++) {
        int gm = m0 + ty * 2 + i;
        if (gm >= M) continue;
        #pragma unroll
        for (int j = 0; j < 4; j++) {
            int gn = n0 + tx * 4 + j;
            float vv = acc[i][j];
            if (bias) vv += bias[gn];
            if (relu) vv = fmaxf(vv, 0.f);
            if (tmode == 1)
                C[(size_t)(gm >> 7) * 65536 + (size_t)gn * SENC + (gm & 127)] = vv;
            else
                C[(size_t)gm * N + gn] = vv;
        }
    }
}

// ---------------------------------------------------------------------------
// Fused QKV: blockIdx.x: sel = x>>3 in {q,k,v}, n-tile = x&7. N=K=512.
// q,v row-major; k TRANSPOSED: kT[((b*8+h)*64+d)*33 + p], gm=p*16+b, gn=h*64+d.
// ---------------------------------------------------------------------------
__global__ __launch_bounds__(256) void gemm_qkv_k(
    const float* __restrict__ A, const float* __restrict__ W0,
    const float* __restrict__ W1, const float* __restrict__ W2,
    float* __restrict__ Cb, int M)
{
    __shared__ __align__(16) float As[2][16][34];
    __shared__ __align__(16) float Bs[2][16][68];
    int sel = blockIdx.x >> 3;
    const float* W = (sel == 0) ? W0 : ((sel == 1) ? W1 : W2);
    float* C = Cb + (size_t)sel * XSZ;
    int tid = threadIdx.x;
    int tx = tid & 15, ty = tid >> 4;
    int m0 = blockIdx.y * 32, n0 = (blockIdx.x & 7) * 64;
    int am = tid >> 2, aseg = tid & 3;
    int bk = tid >> 4, bc4 = (tid & 15) * 4;
    float4 aReg = make_float4(0.f, 0.f, 0.f, 0.f), bReg;
    {
        if (tid < 128) {
            int gm = m0 + am;
            if (gm < M) aReg = *(const float4*)&A[(size_t)gm * D_ + aseg * 4];
        }
        bReg = *(const float4*)&W[(size_t)bk * D_ + n0 + bc4];
    }
    if (tid < 128) {
        As[0][aseg * 4 + 0][am] = aReg.x;
        As[0][aseg * 4 + 1][am] = aReg.y;
        As[0][aseg * 4 + 2][am] = aReg.z;
        As[0][aseg * 4 + 3][am] = aReg.w;
    }
    *(float4*)&Bs[0][bk][bc4] = bReg;
    __syncthreads();
    float acc[2][4] = {};
    for (int it = 0; it < 32; it++) {
        int cur = it & 1;
        if (it + 1 < 32) {
            int k0 = (it + 1) * 16;
            if (tid < 128) {
                int gm = m0 + am;
                aReg = make_float4(0.f, 0.f, 0.f, 0.f);
                if (gm < M) aReg = *(const float4*)&A[(size_t)gm * D_ + k0 + aseg * 4];
            }
            bReg = *(const float4*)&W[(size_t)(k0 + bk) * D_ + n0 + bc4];
        }
        #pragma unroll
        for (int kk = 0; kk < 16; kk++) {
            float2 a2 = *(const float2*)&As[cur][kk][ty * 2];
            float4 b4 = *(const float4*)&Bs[cur][kk][tx * 4];
            acc[0][0] += a2.x * b4.x; acc[0][1] += a2.x * b4.y;
            acc[0][2] += a2.x * b4.z; acc[0][3] += a2.x * b4.w;
            acc[1][0] += a2.y * b4.x; acc[1][1] += a2.y * b4.y;
            acc[1][2] += a2.y * b4.z; acc[1][3] += a2.y * b4.w;
        }
        if (it + 1 < 32) {
            int nxt = 1 - cur;
            if (tid < 128) {
                As[nxt][aseg * 4 + 0][am] = aReg.x;
                As[nxt][aseg * 4 + 1][am] = aReg.y;
                As[nxt][aseg * 4 + 2][am] = aReg.z;
                As[nxt][aseg * 4 + 3][am] = aReg.w;
            }
            *(float4*)&Bs[nxt][bk][bc4] = bReg;
        }
        __syncthreads();
    }
    #pragma unroll
    for (int i = 0; i < 2; i++) {
        int gm = m0 + ty * 2 + i;
        if (gm >= M) continue;
        #pragma unroll
        for (int j = 0; j < 4; j++) {
            int gn = n0 + tx * 4 + j;
            if (sel == 1)
                C[(size_t)(gm & 15) * 16896 + (size_t)gn * TP1 + (gm >> 4)] =
                    acc[i][j];
            else
                C[(size_t)gm * D_ + gn] = acc[i][j];
        }
    }
}

// ---------------------------------------------------------------------------
// FUSED FFN: block (bx = dff-chunk of 128, by = 16-row tile).
// Phase 1: h[16][128] = relu(x_rows @ w1[:, bx*128..+128] + b1[chunk])
//   — same double-buffered skeleton; per-output k-order identical to the
//   old ffn1 GEMM (bitwise-equal h).
// Phase 2: parts[bx] = h @ w2[bx*128..+128, :] — h broadcast from LDS,
//   w2 float4 coalesced, VALU-bound. ln_red then sums 16 parts.
// Replaces ffn1+ffn2 (2 launches -> 1) and kills the ffnh round-trip.
// ---------------------------------------------------------------------------
__global__ __launch_bounds__(256) void ffn_fused_k(
    const float* __restrict__ A, const float* __restrict__ w1,
    const float* __restrict__ b1, const float* __restrict__ w2,
    float* __restrict__ parts, int M)
{
    __shared__ __align__(16) float As[2][16][18];
    __shared__ __align__(16) float Bs[2][16][132];
    __shared__ __align__(16) float hs[16][132];
    int tid = threadIdx.x;
    int bx = blockIdx.x;
    int r0 = blockIdx.y * 16;
    // ---- phase 1: 16x128 GEMM, K=512
    int ty = tid >> 5, tx = tid & 31;        // rows ty*2..+1, col tx*4
    int am = tid >> 2, aseg = tid & 3;       // A loader (tid<64)
    int bk = tid >> 4, bc4 = (tid & 15) * 4; // B loader: 16k x 64c (x2 halves)
    const float* W1c = w1 + bx * 128;
    float4 aReg = make_float4(0.f, 0.f, 0.f, 0.f), bReg0, bReg1;
    {
        if (tid < 64) {
            int gm = r0 + am;
            if (gm < M) aReg = *(const float4*)&A[(size_t)gm * D_ + aseg * 4];
        }
        bReg0 = *(const float4*)&W1c[(size_t)bk * DFF_ + bc4];
        bReg1 = *(const float4*)&W1c[(size_t)bk * DFF_ + bc4 + 64];
    }
    if (tid < 64) {
        As[0][aseg * 4 + 0][am] = aReg.x;
        As[0][aseg * 4 + 1][am] = aReg.y;
        As[0][aseg * 4 + 2][am] = aReg.z;
        As[0][aseg * 4 + 3][am] = aReg.w;
    }
    *(float4*)&Bs[0][bk][bc4]      = bReg0;
    *(float4*)&Bs[0][bk][bc4 + 64] = bReg1;
    __syncthreads();
    float acc[2][4] = {};
    for (int it = 0; it < 32; it++) {
        int cur = it & 1;
        if (it + 1 < 32) {
            int k0 = (it + 1) * 16;
            if (tid < 64) {
                int gm = r0 + am;
                aReg = make_float4(0.f, 0.f, 0.f, 0.f);
                if (gm < M) aReg = *(const float4*)&A[(size_t)gm * D_ + k0 + aseg * 4];
            }
            bReg0 = *(const float4*)&W1c[(size_t)(k0 + bk) * DFF_ + bc4];
            bReg1 = *(const float4*)&W1c[(size_t)(k0 + bk) * DFF_ + bc4 + 64];
        }
        #pragma unroll
        for (int kk = 0; kk < 16; kk++) {
            float2 a2 = *(const float2*)&As[cur][kk][ty * 2];
            float4 b4 = *(const float4*)&Bs[cur][kk][tx * 4];
            acc[0][0] += a2.x * b4.x; acc[0][1] += a2.x * b4.y;
            acc[0][2] += a2.x * b4.z; acc[0][3] += a2.x * b4.w;
            acc[1][0] += a2.y * b4.x; acc[1][1] += a2.y * b4.y;
            acc[1][2] += a2.y * b4.z; acc[1][3] += a2.y * b4.w;
        }
        if (it + 1 < 32) {
            int nxt = 1 - cur;
            if (tid < 64) {
                As[nxt][aseg * 4 + 0][am] = aReg.x;
                As[nxt][aseg * 4 + 1][am] = aReg.y;
                As[nxt][aseg * 4 + 2][am] = aReg.z;
                As[nxt][aseg * 4 + 3][am] = aReg.w;
            }
            *(float4*)&Bs[nxt][bk][bc4]      = bReg0;
            *(float4*)&Bs[nxt][bk][bc4 + 64] = bReg1;
        }
        __syncthreads();
    }
    // bias + relu -> hs
    {
        float4 bv = *(const float4*)&b1[bx * 128 + tx * 4];
        #pragma unroll
        for (int i = 0; i < 2; i++) {
            float4 o;
            o.x = fmaxf(acc[i][0] + bv.x, 0.f);
            o.y = fmaxf(acc[i][1] + bv.y, 0.f);
            o.z = fmaxf(acc[i][2] + bv.z, 0.f);
            o.w = fmaxf(acc[i][3] + bv.w, 0.f);
            *(float4*)&hs[ty * 2 + i][tx * 4] = o;
        }
    }
    __syncthreads();
    // ---- phase 2: parts[bx][16 rows][512] = hs @ w2 chunk
    int rh = tid >> 7, cg = tid & 127;       // 8 rows per half, col cg*4
    float acc2[8][4] = {};
    const float* W2c = w2 + (size_t)(bx * 128) * D_;
    for (int k = 0; k < 128; k++) {
        float4 w4 = *(const float4*)&W2c[(size_t)k * D_ + cg * 4];
        #pragma unroll
        for (int r = 0; r < 8; r++) {
            float h = hs[rh * 8 + r][k];
            acc2[r][0] += h * w4.x; acc2[r][1] += h * w4.y;
            acc2[r][2] += h * w4.z; acc2[r][3] += h * w4.w;
        }
    }
    float* P = parts + (size_t)bx * XSZ;
    #pragma unroll
    for (int r = 0; r < 8; r++) {
        int gm = r0 + rh * 8 + r;
        if (gm < M) {
            float4 o;
            o.x = acc2[r][0]; o.y = acc2[r][1];
            o.z = acc2[r][2]; o.w = acc2[r][3];
            *(float4*)&P[(size_t)gm * D_ + cg * 4] = o;
        }
    }
}

// ---------------------------------------------------------------------------
__global__ void init_k(int* __restrict__ tokens, int* __restrict__ done,
                       float* __restrict__ cmask, const float* __restrict__ pm)
{
    int tid = threadIdx.x + blockIdx.x * 256;
    if (tid < B_ * TP1) tokens[tid] = ((tid % TP1) == 0) ? 1 : 0;
    if (tid < B_) done[tid] = 0;
    if (tid < B_ * SENC) cmask[tid] = pm[tid] * NEGV;
}

// ---------------------------------------------------------------------------
__global__ __launch_bounds__(256) void pe_k(float* __restrict__ pe)
{
    int p = blockIdx.x;
    for (int d = threadIdx.x; d < D_; d += 256) {
        float fd = (float)(2 * (d / 2)) / (float)D_;
        float ang = (float)p / powf(10000.f, fd);
        pe[(size_t)p * D_ + d] = (d & 1) ? cosf(ang) : sinf(ang);
    }
}

// ---------------------------------------------------------------------------
// Fused embed + (for the p==t block) argmax of previous step's logits.
// ---------------------------------------------------------------------------
__global__ __launch_bounds__(256) void embed_k(
    const float* __restrict__ embed, int* __restrict__ tokens,
    float* __restrict__ x, const float* __restrict__ pe,
    const float* __restrict__ cand_v, const int* __restrict__ cand_i,
    int* __restrict__ done, int t)
{
    int p = blockIdx.x;
    int b = blockIdx.y;
    int tid = threadIdx.x;
    __shared__ float sv[128];
    __shared__ int si[128];
    __shared__ int stok;
    if (p == t && t > 0) {
        if (tid < 128) {
            float val = -1e30f; int idx = 0x7fffffff;
            if (tid < 125) {
                val = cand_v[(size_t)b * 125 + tid];
                idx = cand_i[(size_t)b * 125 + tid];
            }
            sv[tid] = val; si[tid] = idx;
        }
        __syncthreads();
        for (int s = 64; s; s >>= 1) {
            if (tid < s) {
                float ov = sv[tid + s]; int oi = si[tid + s];
                if (ov > sv[tid] || (ov == sv[tid] && oi < si[tid])) {
                    sv[tid] = ov; si[tid] = oi;
                }
            }
            __syncthreads();
        }
        if (tid == 0) {
            int best = si[0];
            int dn = done[b] | (best == 2 ? 1 : 0);
            done[b] = dn;
            int tk = dn ? 0 : best;
            tokens[b * TP1 + t] = tk;
            stok = tk;
        }
        __syncthreads();
    }
    int tok = (p == t && t > 0) ? stok : tokens[b * TP1 + p];
    const float* e = embed + (size_t)tok * D_;
    const float* pr = pe + (size_t)p * D_;
    float* xr = x + ((size_t)p * B_ + b) * D_;
    int c0 = tid * 2;
    float2 ev = *(const float2*)&e[c0];
    float2 pv = *(const float2*)&pr[c0];
    float2 o;
    o.x = ev.x * SQRTD + pv.x;
    o.y = ev.y * SQRTD + pv.y;
    *(float2*)&xr[c0] = o;
}

// ---------------------------------------------------------------------------
__device__ __forceinline__ float block_sum(float s) {
    __shared__ float red[4];
    #pragma unroll
    for (int off = 32; off; off >>= 1) s += __shfl_xor(s, off);
    if ((threadIdx.x & 63) == 0) red[threadIdx.x >> 6] = s;
    __syncthreads();
    float tot = red[0] + red[1] + red[2] + red[3];
    __syncthreads();
    return tot;
}

__device__ __forceinline__ float4 block_sum4(float4 s) {
    __shared__ __align__(16) float red4[4][4];
    #pragma unroll
    for (int off = 32; off; off >>= 1) {
        s.x += __shfl_xor(s.x, off);
        s.y += __shfl_xor(s.y, off);
        s.z += __shfl_xor(s.z, off);
        s.w += __shfl_xor(s.w, off);
    }
    if ((threadIdx.x & 63) == 0) *(float4*)red4[threadIdx.x >> 6] = s;
    __syncthreads();
    float4 t;
    t.x = red4[0][0] + red4[1][0] + red4[2][0] + red4[3][0];
    t.y = red4[0][1] + red4[1][1] + red4[2][1] + red4[3][1];
    t.z = red4[0][2] + red4[1][2] + red4[2][2] + red4[3][2];
    t.w = red4[0][3] + red4[1][3] + red4[2][3] + red4[3][3];
    __syncthreads();
    return t;
}

// ---------------------------------------------------------------------------
// MEGA: self-attn + wo + LN + cross(q-proj, attn, cwo) + LN. G=4 rows of the
// SAME batch per block. Row-major float2 weight loops (wave-coalesced).
// ---------------------------------------------------------------------------
__global__ __launch_bounds__(256) void attn_mega_k(
    const float* __restrict__ q, const float* __restrict__ kT,
    const float* __restrict__ v, const float* __restrict__ wo,
    const float* __restrict__ KcT, const float* __restrict__ Vc,
    const float* __restrict__ cmask, const float* __restrict__ cwq,
    const float* __restrict__ cwo, float* __restrict__ x,
    const float* __restrict__ lg, const float* __restrict__ lb, int P)
{
    int b = blockIdx.x;
    int p0 = blockIdx.y * 4;
    int tid = threadIdx.x;
    int c0 = tid * 2;
    __shared__ float xs[4][D_];
    __shared__ float arow[4][D_];
    __shared__ float scs[4][H_][SENC + 4];
    __shared__ float inv[4][H_];
    #pragma unroll
    for (int g = 0; g < 4; g++) {
        float2 qv = make_float2(0.f, 0.f);
        if (p0 + g < P)
            qv = *(const float2*)&q[((size_t)(p0 + g) * B_ + b) * D_ + c0];
        *(float2*)&arow[g][c0] = qv;
    }
    __syncthreads();
    {
        int h = tid >> 5, kp = tid & 31;
        float a0 = 0.f, a1 = 0.f, a2 = 0.f, a3 = 0.f;
        if (kp < P) {
            const float* kb = kT + ((size_t)(b * 8 + h) * 64) * TP1 + kp;
            #pragma unroll 8
            for (int d = 0; d < 64; d++) {
                float kv = kb[(size_t)d * TP1];
                a0 += arow[0][h * 64 + d] * kv;
                a1 += arow[1][h * 64 + d] * kv;
                a2 += arow[2][h * 64 + d] * kv;
                a3 += arow[3][h * 64 + d] * kv;
            }
        }
        scs[0][h][kp] = a0 * 0.125f;
        scs[1][h][kp] = a1 * 0.125f;
        scs[2][h][kp] = a2 * 0.125f;
        scs[3][h][kp] = a3 * 0.125f;
    }
    __syncthreads();
    {
        int gh = tid >> 3, lane8 = tid & 7;
        int g = gh >> 3, h = gh & 7;
        float mx = -1e30f;
        for (int j = lane8; j < P; j += 8) mx = fmaxf(mx, scs[g][h][j]);
        mx = fmaxf(mx, __shfl_xor(mx, 1));
        mx = fmaxf(mx, __shfl_xor(mx, 2));
        mx = fmaxf(mx, __shfl_xor(mx, 4));
        float sum = 0.f;
        for (int j = lane8; j < P; j += 8) {
            float e = expf(scs[g][h][j] - mx);
            scs[g][h][j] = e;
            sum += e;
        }
        sum += __shfl_xor(sum, 1);
        sum += __shfl_xor(sum, 2);
        sum += __shfl_xor(sum, 4);
        if (lane8 == 0) inv[g][h] = 1.f / sum;
    }
    __syncthreads();
    {
        int h = tid >> 5;
        float o0[4] = {0.f, 0.f, 0.f, 0.f}, o1[4] = {0.f, 0.f, 0.f, 0.f};
        for (int j = 0; j < P; j++) {
            float2 vv = *(const float2*)&v[((size_t)j * B_ + b) * D_ + c0];
            #pragma unroll
            for (int g = 0; g < 4; g++) {
                float w = scs[g][h][j];
                o0[g] += w * vv.x; o1[g] += w * vv.y;
            }
        }
        #pragma unroll
        for (int g = 0; g < 4; g++) {
            arow[g][c0]     = o0[g] * inv[g][h];
            arow[g][c0 + 1] = o1[g] * inv[g][h];
        }
    }
    __syncthreads();
    {
        float v0[4], v1[4];
        #pragma unroll
        for (int g = 0; g < 4; g++) {
            float2 xv = make_float2(0.f, 0.f);
            if (p0 + g < P)
                xv = *(const float2*)&x[((size_t)(p0 + g) * B_ + b) * D_ + c0];
            v0[g] = xv.x; v1[g] = xv.y;
        }
        #pragma unroll 8
        for (int k = 0; k < D_; k++) {
            float2 wv = *(const float2*)&wo[(size_t)k * D_ + c0];
            #pragma unroll
            for (int g = 0; g < 4; g++) {
                float a = arow[g][k];
                v0[g] += a * wv.x; v1[g] += a * wv.y;
            }
        }
        float4 s1 = make_float4(v0[0] + v1[0], v0[1] + v1[1],
                                v0[2] + v1[2], v0[3] + v1[3]);
        float4 m4 = block_sum4(s1);
        float mean[4] = {m4.x * (1.f / 512.f), m4.y * (1.f / 512.f),
                         m4.z * (1.f / 512.f), m4.w * (1.f / 512.f)};
        float d0[4], d1[4];
        #pragma unroll
        for (int g = 0; g < 4; g++) {
            d0[g] = v0[g] - mean[g]; d1[g] = v1[g] - mean[g];
        }
        float4 s2 = make_float4(d0[0] * d0[0] + d1[0] * d1[0],
                                d0[1] * d0[1] + d1[1] * d1[1],
                                d0[2] * d0[2] + d1[2] * d1[2],
                                d0[3] * d0[3] + d1[3] * d1[3]);
        float4 w4 = block_sum4(s2);
        float var[4] = {w4.x * (1.f / 512.f), w4.y * (1.f / 512.f),
                        w4.z * (1.f / 512.f), w4.w * (1.f / 512.f)};
        float g0 = lg[c0], g1 = lg[c0 + 1];
        float bb0 = lb[c0], bb1 = lb[c0 + 1];
        #pragma unroll
        for (int g = 0; g < 4; g++) {
            float rs = rsqrtf(var[g] + EPSV);
            xs[g][c0]     = d0[g] * rs * g0 + bb0;
            xs[g][c0 + 1] = d1[g] * rs * g1 + bb1;
        }
    }
    __syncthreads();
    {
        float q0[4] = {0.f, 0.f, 0.f, 0.f}, q1[4] = {0.f, 0.f, 0.f, 0.f};
        #pragma unroll 8
        for (int k = 0; k < D_; k++) {
            float2 wv = *(const float2*)&cwq[(size_t)k * D_ + c0];
            #pragma unroll
            for (int g = 0; g < 4; g++) {
                float a = xs[g][k];
                q0[g] += a * wv.x; q1[g] += a * wv.y;
            }
        }
        #pragma unroll
        for (int g = 0; g < 4; g++) {
            arow[g][c0] = q0[g]; arow[g][c0 + 1] = q1[g];
        }
    }
    __syncthreads();
    #pragma unroll
    for (int i = 0; i < 4; i++) {
        int idx = tid + i * 256;
        int h = idx >> 7, s = idx & 127;
        const float* kb = KcT + ((size_t)(b * 512 + h * 64)) * SENC + s;
        float a0 = 0.f, a1 = 0.f, a2 = 0.f, a3 = 0.f;
        #pragma unroll 8
        for (int d = 0; d < 64; d++) {
            float kc = kb[(size_t)d * SENC];
            a0 += arow[0][h * 64 + d] * kc;
            a1 += arow[1][h * 64 + d] * kc;
            a2 += arow[2][h * 64 + d] * kc;
            a3 += arow[3][h * 64 + d] * kc;
        }
        float cm = cmask[b * SENC + s];
        scs[0][h][s] = a0 * 0.125f + cm;
        scs[1][h][s] = a1 * 0.125f + cm;
        scs[2][h][s] = a2 * 0.125f + cm;
        scs[3][h][s] = a3 * 0.125f + cm;
    }
    __syncthreads();
    {
        int gh = tid >> 3, lane8 = tid & 7;
        int g = gh >> 3, h = gh & 7;
        float mx = -1e30f;
        for (int s = lane8; s < SENC; s += 8) mx = fmaxf(mx, scs[g][h][s]);
        mx = fmaxf(mx, __shfl_xor(mx, 1));
        mx = fmaxf(mx, __shfl_xor(mx, 2));
        mx = fmaxf(mx, __shfl_xor(mx, 4));
        float sum = 0.f;
        for (int s = lane8; s < SENC; s += 8) {
            float e = expf(scs[g][h][s] - mx);
            scs[g][h][s] = e;
            sum += e;
        }
        sum += __shfl_xor(sum, 1);
        sum += __shfl_xor(sum, 2);
        sum += __shfl_xor(sum, 4);
        if (lane8 == 0) inv[g][h] = 1.f / sum;
    }
    __syncthreads();
    {
        int h = tid >> 5;
        float o0[4] = {0.f, 0.f, 0.f, 0.f}, o1[4] = {0.f, 0.f, 0.f, 0.f};
        for (int s = 0; s < SENC; s++) {
            float2 vv = *(const float2*)&Vc[((size_t)b * SENC + s) * D_ + c0];
            #pragma unroll
            for (int g = 0; g < 4; g++) {
                float w = scs[g][h][s];
                o0[g] += w * vv.x; o1[g] += w * vv.y;
            }
        }
        #pragma unroll
        for (int g = 0; g < 4; g++) {
            arow[g][c0]     = o0[g] * inv[g][h];
            arow[g][c0 + 1] = o1[g] * inv[g][h];
        }
    }
    __syncthreads();
    {
        float v0[4], v1[4];
        #pragma unroll
        for (int g = 0; g < 4; g++) {
            v0[g] = xs[g][c0]; v1[g] = xs[g][c0 + 1];
        }
        #pragma unroll 8
        for (int k = 0; k < D_; k++) {
            float2 wv = *(const float2*)&cwo[(size_t)k * D_ + c0];
            #pragma unroll
            for (int g = 0; g < 4; g++) {
                float a = arow[g][k];
                v0[g] += a * wv.x; v1[g] += a * wv.y;
            }
        }
        float4 s1 = make_float4(v0[0] + v1[0], v0[1] + v1[1],
                                v0[2] + v1[2], v0[3] + v1[3]);
        float4 m4 = block_sum4(s1);
        float mean[4] = {m4.x * (1.f / 512.f), m4.y * (1.f / 512.f),
                         m4.z * (1.f / 512.f), m4.w * (1.f / 512.f)};
        float d0[4], d1[4];
        #pragma unroll
        for (int g = 0; g < 4; g++) {
            d0[g] = v0[g] - mean[g]; d1[g] = v1[g] - mean[g];
        }
        float4 s2 = make_float4(d0[0] * d0[0] + d1[0] * d1[0],
                                d0[1] * d0[1] + d1[1] * d1[1],
                                d0[2] * d0[2] + d1[2] * d1[2],
                                d0[3] * d0[3] + d1[3] * d1[3]);
        float4 w4 = block_sum4(s2);
        float var[4] = {w4.x * (1.f / 512.f), w4.y * (1.f / 512.f),
                        w4.z * (1.f / 512.f), w4.w * (1.f / 512.f)};
        float g0 = lg[D_ + c0], g1 = lg[D_ + c0 + 1];
        float bb0 = lb[D_ + c0], bb1 = lb[D_ + c0 + 1];
        #pragma unroll
        for (int g = 0; g < 4; g++) {
            if (p0 + g < P) {
                float rs = rsqrtf(var[g] + EPSV);
                float* xr = x + ((size_t)(p0 + g) * B_ + b) * D_;
                xr[c0]     = d0[g] * rs * g0 + bb0;
                xr[c0 + 1] = d1[g] * rs * g1 + bb1;
            }
        }
    }
}

// ---------------------------------------------------------------------------
// x = LN(x + sum_parts (+ bias)) * g + b. One block per row.
// ---------------------------------------------------------------------------
__global__ __launch_bounds__(256) void ln_red_k(
    float* __restrict__ x, const float* __restrict__ parts, size_t pstride,
    int nparts, const float* __restrict__ bias,
    const float* __restrict__ gam, const float* __restrict__ bet)
{
    int r = blockIdx.x;
    float* xr = x + (size_t)r * D_;
    int tid = threadIdx.x;
    float v0 = xr[tid];
    float v1 = xr[tid + 256];
    for (int s = 0; s < nparts; s++) {
        const float* pr = parts + (size_t)s * pstride + (size_t)r * D_;
        v0 += pr[tid];
        v1 += pr[tid + 256];
    }
    if (bias) { v0 += bias[tid]; v1 += bias[tid + 256]; }
    float mean = block_sum(v0 + v1) * (1.f / 512.f);
    float d0 = v0 - mean, d1 = v1 - mean;
    float var = block_sum(d0 * d0 + d1 * d1) * (1.f / 512.f);
    float rs = rsqrtf(var + EPSV);
    xr[tid]       = d0 * rs * gam[tid] + bet[tid];
    xr[tid + 256] = d1 * rs * gam[tid + 256] + bet[tid + 256];
}

// ---------------------------------------------------------------------------
// logits -> per-block argmax candidates (R3 LDS-staged form — best measured).
// ---------------------------------------------------------------------------
__global__ __launch_bounds__(256) void logits_k(
    const float* __restrict__ x, const float* __restrict__ fcw,
    const float* __restrict__ fcb, float* __restrict__ cand_v,
    int* __restrict__ cand_i, int t)
{
    __shared__ float xs[B_][D_];
    __shared__ float red[4][64][B_];
    int tid = threadIdx.x;
    for (int i = tid; i < B_ * D_; i += 256) {
        int b = i >> 9, d = i & 511;
        xs[b][d] = x[((size_t)t * B_ + b) * D_ + d];
    }
    __syncthreads();
    int lane = tid & 63, ks = tid >> 6;
    int col = blockIdx.x * 64 + lane;
    float acc[B_] = {};
    int kb = ks * 128;
    for (int k = kb; k < kb + 128; k++) {
        float w = fcw[(size_t)k * V_ + col];
        #pragma unroll
        for (int b = 0; b < B_; b++) acc[b] += xs[b][k] * w;
    }
    #pragma unroll
    for (int b = 0; b < B_; b++) red[ks][lane][b] = acc[b];
    __syncthreads();
    if (ks == 0) {
        float bias = fcb[col];
        #pragma unroll
        for (int b = 0; b < B_; b++) {
            float val = red[0][lane][b] + red[1][lane][b]
                      + red[2][lane][b] + red[3][lane][b] + bias;
            int idx = col;
            #pragma unroll
            for (int off = 32; off; off >>= 1) {
                float ov = __shfl_down(val, off);
                int oi = __shfl_down(idx, off);
                if (ov > val || (ov == val && oi < idx)) { val = ov; idx = oi; }
            }
            if (lane == 0) {
                cand_v[(size_t)b * 125 + blockIdx.x] = val;
                cand_i[(size_t)b * 125 + blockIdx.x] = idx;
            }
        }
    }
}

// ---------------------------------------------------------------------------
__global__ __launch_bounds__(128) void writeout_k(
    const int* __restrict__ tokens, const float* __restrict__ cand_v,
    const int* __restrict__ cand_i, const int* __restrict__ done,
    int* __restrict__ out)
{
    int b = blockIdx.x;
    int tid = threadIdx.x;
    __shared__ float sv[128];
    __shared__ int si[128];
    __shared__ int stok;
    float val = -1e30f; int idx = 0x7fffffff;
    if (tid < 125) {
        val = cand_v[(size_t)b * 125 + tid];
        idx = cand_i[(size_t)b * 125 + tid];
    }
    sv[tid] = val; si[tid] = idx;
    __syncthreads();
    for (int s = 64; s; s >>= 1) {
        if (tid < s) {
            float ov = sv[tid + s]; int oi = si[tid + s];
            if (ov > sv[tid] || (ov == sv[tid] && oi < si[tid])) {
                sv[tid] = ov; si[tid] = oi;
            }
        }
        __syncthreads();
    }
    if (tid == 0) {
        int best = si[0];
        int dn = done[b] | (best == 2 ? 1 : 0);
        stok = dn ? 0 : best;
    }
    __syncthreads();
    if (tid < T_)
        out[b * T_ + tid] = (tid == T_ - 1) ? stok : tokens[b * TP1 + tid + 1];
}

// ---------------------------------------------------------------------------
extern "C" void kernel_launch(void* const* d_in, const int* in_sizes, int n_in,
                              void* d_out, int out_size, void* d_ws, size_t ws_size,
                              hipStream_t stream)
{
    const float* enc   = (const float*)d_in[1];
    const float* pm    = (const float*)d_in[2];
    const float* embed = (const float*)d_in[3];
    const float* wq    = (const float*)d_in[4];
    const float* wk    = (const float*)d_in[5];
    const float* wv    = (const float*)d_in[6];
    const float* wo    = (const float*)d_in[7];
    const float* cwq   = (const float*)d_in[8];
    const float* cwk   = (const float*)d_in[9];
    const float* cwv   = (const float*)d_in[10];
    const float* cwo   = (const float*)d_in[11];
    const float* w1    = (const float*)d_in[12];
    const float* b1    = (const float*)d_in[13];
    const float* w2    = (const float*)d_in[14];
    const float* b2    = (const float*)d_in[15];
    const float* ln_g  = (const float*)d_in[16];
    const float* ln_b  = (const float*)d_in[17];
    const float* fcw   = (const float*)d_in[18];
    const float* fcb   = (const float*)d_in[19];

    float* ws = (float*)d_ws;
    size_t off = 0;
    float* x     = ws + off; off += XSZ;
    float* qkv   = ws + off; off += 3 * XSZ;      // q | kT | v
    float* parts = ws + off; off += NCH * XSZ;    // 16 dff-chunk partials
    float* ffnh  = parts + 4 * XSZ;               // alias (fallback only):
                                                  // 4*XSZ == 33*16*2048 exactly
    float* cand_v= ws + off; off += (size_t)B_ * 125;
    float* KcT   = ws + off; off += (size_t)L_ * B_ * SENC * D_;
    float* Vc    = ws + off; off += (size_t)L_ * B_ * SENC * D_;
    float* cmask = ws + off; off += (size_t)B_ * SENC;
    float* pe    = ws + off; off += (size_t)TP1 * D_;
    int* cand_i  = (int*)(ws + off); off += (size_t)B_ * 125;
    int* tokens  = (int*)(ws + off); off += (B_ * TP1 + 63) & ~63;
    int* done    = (int*)(ws + off); off += 64;
    // ws evidence: R2's 59.2MB layout executed -> ws_size >= 59.2MB; this
    // layout needs 55.3MB. Guard anyway: fused FFN iff it fits.
    int fused = (ws_size >= off * sizeof(float)) ? 1 : 0;

    init_k<<<8, 256, 0, stream>>>(tokens, done, cmask, pm);
    pe_k<<<TP1, 256, 0, stream>>>(pe);

    const size_t KVL = (size_t)B_ * SENC * D_;
    for (int l = 0; l < L_; l++) {
        gemm32_k<<<dim3(8, (B_ * SENC) / 32), 256, 0, stream>>>(
            enc, cwk + (size_t)l * D_ * D_, nullptr, KcT + l * KVL,
            B_ * SENC, D_, D_, D_, 0, 0, 1);
        gemm32_k<<<dim3(8, (B_ * SENC) / 32), 256, 0, stream>>>(
            enc, cwv + (size_t)l * D_ * D_, nullptr, Vc + l * KVL,
            B_ * SENC, D_, D_, D_, 0, 0, 0);
    }

    for (int t = 0; t < T_; t++) {
        int P = t + 1;
        int M = P * B_;
        int mt = (M + 31) / 32;

        embed_k<<<dim3(P, B_), 256, 0, stream>>>(
            embed, tokens, x, pe, cand_v, cand_i, done, t);

        for (int l = 0; l < L_; l++) {
            const size_t lw = (size_t)l * D_ * D_;
            gemm_qkv_k<<<dim3(24, mt), 256, 0, stream>>>(
                x, wq + lw, wk + lw, wv + lw, qkv, M);
            attn_mega_k<<<dim3(B_, (P + 3) / 4), 256, 0, stream>>>(
                qkv, qkv + XSZ, qkv + 2 * XSZ, wo + lw,
                KcT + l * KVL, Vc + l * KVL, cmask, cwq + lw, cwo + lw, x,
                ln_g + (size_t)(l * 3 + 0) * D_, ln_b + (size_t)(l * 3 + 0) * D_, P);
            if (fused) {
                ffn_fused_k<<<dim3(NCH, (M + 15) / 16), 256, 0, stream>>>(
                    x, w1 + (size_t)l * D_ * DFF_, b1 + (size_t)l * DFF_,
                    w2 + (size_t)l * DFF_ * D_, parts, M);
                ln_red_k<<<M, 256, 0, stream>>>(x, parts, XSZ, NCH,
                    b2 + (size_t)l * D_,
                    ln_g + (size_t)(l * 3 + 2) * D_, ln_b + (size_t)(l * 3 + 2) * D_);
            } else {
                gemm32_k<<<dim3(32, mt), 256, 0, stream>>>(
                    x, w1 + (size_t)l * D_ * DFF_, b1 + (size_t)l * DFF_, ffnh,
                    M, DFF_, D_, D_, 0, 1, 0);
                gemm32_k<<<dim3(8, mt, 4), 256, 0, stream>>>(
                    ffnh, w2 + (size_t)l * DFF_ * D_, nullptr, parts,
                    M, D_, DFF_, 512, XSZ, 0, 0);
                ln_red_k<<<M, 256, 0, stream>>>(x, parts, XSZ, 4,
                    b2 + (size_t)l * D_,
                    ln_g + (size_t)(l * 3 + 2) * D_, ln_b + (size_t)(l * 3 + 2) * D_);
            }
        }

        logits_k<<<V_ / 64, 256, 0, stream>>>(x, fcw, fcb, cand_v, cand_i, t);
    }

    writeout_k<<<B_, 128, 0, stream>>>(tokens, cand_v, cand_i, done, (int*)d_out);
}

// Round 10
// 22778.891 us; speedup vs baseline: 3.8247x; 1.0362x over previous
//
#include <hip/hip_runtime.h>
#include <math.h>

#define L_   4
#define H_   8
#define D_   512
#define DH   64
#define DFF_ 2048
#define V_   8000
#define B_   16
#define SENC 128
#define T_   32
#define TP1  33
#define NEGV -1e9f
#define EPSV 1e-6f
#define SQRTD 22.627416997969522f   // sqrt(512)
#define XSZ  ((size_t)TP1 * B_ * D_)   // 270336 floats
#define NCH  16                         // dff chunks (2048/128)

// ---------------------------------------------------------------------------
// fp32 GEMM, 32x64 tile, 256 threads (2x4 micro-tile), double-buffered LDS,
// BK=32 K-step (16 barriers per K=512 instead of 32; FMA order per output
// stays k-ascending -> bitwise identical). float4 global loads.
// tmode==1: KcT transpose epilogue. kchunk must be a multiple of 32.
// ---------------------------------------------------------------------------
__global__ __launch_bounds__(256) void gemm32_k(
    const float* __restrict__ A, const float* __restrict__ W,
    const float* __restrict__ bias, float* __restrict__ C,
    int M, int N, int K, int kchunk, size_t pstride, int relu, int tmode)
{
    __shared__ __align__(16) float As[2][32][34];
    __shared__ __align__(16) float Bs[2][32][68];
    int tid = threadIdx.x;
    int tx = tid & 15, ty = tid >> 4;          // tx: 4 cols, ty: 2 rows
    int m0 = blockIdx.y * 32, n0 = blockIdx.x * 64;
    int kbeg = blockIdx.z * kchunk;
    int niter = kchunk >> 5;
    C += (size_t)blockIdx.z * pstride;
    int am = tid & 31, aseg = tid >> 5;        // A: 32 rows x 8 k-segs (all thr)
    int bk = tid >> 4, bc4 = (tid & 15) * 4;   // B: k rows bk & bk+16
    float4 aReg, bReg0, bReg1;
    {
        int gm = m0 + am;
        aReg = make_float4(0.f, 0.f, 0.f, 0.f);
        if (gm < M) aReg = *(const float4*)&A[(size_t)gm * K + kbeg + aseg * 4];
        bReg0 = *(const float4*)&W[(size_t)(kbeg + bk) * N + n0 + bc4];
        bReg1 = *(const float4*)&W[(size_t)(kbeg + bk + 16) * N + n0 + bc4];
    }
    As[0][aseg * 4 + 0][am] = aReg.x;
    As[0][aseg * 4 + 1][am] = aReg.y;
    As[0][aseg * 4 + 2][am] = aReg.z;
    As[0][aseg * 4 + 3][am] = aReg.w;
    *(float4*)&Bs[0][bk][bc4]      = bReg0;
    *(float4*)&Bs[0][bk + 16][bc4] = bReg1;
    __syncthreads();
    float acc[2][4] = {};
    for (int it = 0; it < niter; it++) {
        int cur = it & 1;
        if (it + 1 < niter) {
            int k0 = kbeg + (it + 1) * 32;
            int gm = m0 + am;
            aReg = make_float4(0.f, 0.f, 0.f, 0.f);
            if (gm < M) aReg = *(const float4*)&A[(size_t)gm * K + k0 + aseg * 4];
            bReg0 = *(const float4*)&W[(size_t)(k0 + bk) * N + n0 + bc4];
            bReg1 = *(const float4*)&W[(size_t)(k0 + bk + 16) * N + n0 + bc4];
        }
        #pragma unroll
        for (int kk = 0; kk < 32; kk++) {
            float2 a2 = *(const float2*)&As[cur][kk][ty * 2];
            float4 b4 = *(const float4*)&Bs[cur][kk][tx * 4];
            acc[0][0] += a2.x * b4.x; acc[0][1] += a2.x * b4.y;
            acc[0][2] += a2.x * b4.z; acc[0][3] += a2.x * b4.w;
            acc[1][0] += a2.y * b4.x; acc[1][1] += a2.y * b4.y;
            acc[1][2] += a2.y * b4.z; acc[1][3] += a2.y * b4.w;
        }
        if (it + 1 < niter) {
            int nxt = 1 - cur;
            As[nxt][aseg * 4 + 0][am] = aReg.x;
            As[nxt][aseg * 4 + 1][am] = aReg.y;
            As[nxt][aseg * 4 + 2][am] = aReg.z;
            As[nxt][aseg * 4 + 3][am] = aReg.w;
            *(float4*)&Bs[nxt][bk][bc4]      = bReg0;
            *(float4*)&Bs[nxt][bk + 16][bc4] = bReg1;
        }
        __syncthreads();
    }
    #pragma unroll
    for (int i = 0; i < 2; i++) {
        int gm = m0 + ty * 2 + i;
        if (gm >= M) continue;
        #pragma unroll
        for (int j = 0; j < 4; j++) {
            int gn = n0 + tx * 4 + j;
            float vv = acc[i][j];
            if (bias) vv += bias[gn];
            if (relu) vv = fmaxf(vv, 0.f);
            if (tmode == 1)
                C[(size_t)(gm >> 7) * 65536 + (size_t)gn * SENC + (gm & 127)] = vv;
            else
                C[(size_t)gm * N + gn] = vv;
        }
    }
}

// ---------------------------------------------------------------------------
// Fused QKV: blockIdx.x: sel = x>>3 in {q,k,v}, n-tile = x&7. N=K=512.
// BK=32 (16 barrier pairs). q,v row-major; k TRANSPOSED:
// kT[((b*8+h)*64+d)*33 + p], gm=p*16+b, gn=h*64+d.
// ---------------------------------------------------------------------------
__global__ __launch_bounds__(256) void gemm_qkv_k(
    const float* __restrict__ A, const float* __restrict__ W0,
    const float* __restrict__ W1, const float* __restrict__ W2,
    float* __restrict__ Cb, int M)
{
    __shared__ __align__(16) float As[2][32][34];
    __shared__ __align__(16) float Bs[2][32][68];
    int sel = blockIdx.x >> 3;
    const float* W = (sel == 0) ? W0 : ((sel == 1) ? W1 : W2);
    float* C = Cb + (size_t)sel * XSZ;
    int tid = threadIdx.x;
    int tx = tid & 15, ty = tid >> 4;
    int m0 = blockIdx.y * 32, n0 = (blockIdx.x & 7) * 64;
    int am = tid & 31, aseg = tid >> 5;
    int bk = tid >> 4, bc4 = (tid & 15) * 4;
    float4 aReg, bReg0, bReg1;
    {
        int gm = m0 + am;
        aReg = make_float4(0.f, 0.f, 0.f, 0.f);
        if (gm < M) aReg = *(const float4*)&A[(size_t)gm * D_ + aseg * 4];
        bReg0 = *(const float4*)&W[(size_t)bk * D_ + n0 + bc4];
        bReg1 = *(const float4*)&W[(size_t)(bk + 16) * D_ + n0 + bc4];
    }
    As[0][aseg * 4 + 0][am] = aReg.x;
    As[0][aseg * 4 + 1][am] = aReg.y;
    As[0][aseg * 4 + 2][am] = aReg.z;
    As[0][aseg * 4 + 3][am] = aReg.w;
    *(float4*)&Bs[0][bk][bc4]      = bReg0;
    *(float4*)&Bs[0][bk + 16][bc4] = bReg1;
    __syncthreads();
    float acc[2][4] = {};
    for (int it = 0; it < 16; it++) {
        int cur = it & 1;
        if (it + 1 < 16) {
            int k0 = (it + 1) * 32;
            int gm = m0 + am;
            aReg = make_float4(0.f, 0.f, 0.f, 0.f);
            if (gm < M) aReg = *(const float4*)&A[(size_t)gm * D_ + k0 + aseg * 4];
            bReg0 = *(const float4*)&W[(size_t)(k0 + bk) * D_ + n0 + bc4];
            bReg1 = *(const float4*)&W[(size_t)(k0 + bk + 16) * D_ + n0 + bc4];
        }
        #pragma unroll
        for (int kk = 0; kk < 32; kk++) {
            float2 a2 = *(const float2*)&As[cur][kk][ty * 2];
            float4 b4 = *(const float4*)&Bs[cur][kk][tx * 4];
            acc[0][0] += a2.x * b4.x; acc[0][1] += a2.x * b4.y;
            acc[0][2] += a2.x * b4.z; acc[0][3] += a2.x * b4.w;
            acc[1][0] += a2.y * b4.x; acc[1][1] += a2.y * b4.y;
            acc[1][2] += a2.y * b4.z; acc[1][3] += a2.y * b4.w;
        }
        if (it + 1 < 16) {
            int nxt = 1 - cur;
            As[nxt][aseg * 4 + 0][am] = aReg.x;
            As[nxt][aseg * 4 + 1][am] = aReg.y;
            As[nxt][aseg * 4 + 2][am] = aReg.z;
            As[nxt][aseg * 4 + 3][am] = aReg.w;
            *(float4*)&Bs[nxt][bk][bc4]      = bReg0;
            *(float4*)&Bs[nxt][bk + 16][bc4] = bReg1;
        }
        __syncthreads();
    }
    #pragma unroll
    for (int i = 0; i < 2; i++) {
        int gm = m0 + ty * 2 + i;
        if (gm >= M) continue;
        #pragma unroll
        for (int j = 0; j < 4; j++) {
            int gn = n0 + tx * 4 + j;
            if (sel == 1)
                C[(size_t)(gm & 15) * 16896 + (size_t)gn * TP1 + (gm >> 4)] =
                    acc[i][j];
            else
                C[(size_t)gm * D_ + gn] = acc[i][j];
        }
    }
}

// ---------------------------------------------------------------------------
// FUSED FFN: block (bx = dff-chunk of 128, by = 16-row tile).
// Phase 1: h[16][128] = relu(x_rows @ w1 chunk + b1), BK=32 skeleton,
//   k-ascending per output (bitwise-equal h).
// Phase 2: parts[bx] = h @ w2 chunk — hs float4 reads, k-ascending adds.
// ---------------------------------------------------------------------------
__global__ __launch_bounds__(256) void ffn_fused_k(
    const float* __restrict__ A, const float* __restrict__ w1,
    const float* __restrict__ b1, const float* __restrict__ w2,
    float* __restrict__ parts, int M)
{
    __shared__ __align__(16) float As[2][32][18];
    __shared__ __align__(16) float Bs[2][32][132];
    __shared__ __align__(16) float hs[16][132];
    int tid = threadIdx.x;
    int bx = blockIdx.x;
    int r0 = blockIdx.y * 16;
    // ---- phase 1: 16x128 GEMM, K=512, BK=32
    int ty = tid >> 5, tx = tid & 31;        // rows ty*2..+1, col tx*4
    int am = tid & 15, aseg = tid >> 4;      // A loader (tid<128): 16r x 8kseg
    int bk = tid >> 4, bc4 = (tid & 15) * 4; // B: rows bk,bk+16 x 2 col halves
    const float* W1c = w1 + bx * 128;
    float4 aReg = make_float4(0.f, 0.f, 0.f, 0.f);
    float4 bReg00, bReg01, bReg10, bReg11;
    {
        if (tid < 128) {
            int gm = r0 + am;
            if (gm < M) aReg = *(const float4*)&A[(size_t)gm * D_ + aseg * 4];
        }
        bReg00 = *(const float4*)&W1c[(size_t)bk * DFF_ + bc4];
        bReg01 = *(const float4*)&W1c[(size_t)bk * DFF_ + bc4 + 64];
        bReg10 = *(const float4*)&W1c[(size_t)(bk + 16) * DFF_ + bc4];
        bReg11 = *(const float4*)&W1c[(size_t)(bk + 16) * DFF_ + bc4 + 64];
    }
    if (tid < 128) {
        As[0][aseg * 4 + 0][am] = aReg.x;
        As[0][aseg * 4 + 1][am] = aReg.y;
        As[0][aseg * 4 + 2][am] = aReg.z;
        As[0][aseg * 4 + 3][am] = aReg.w;
    }
    *(float4*)&Bs[0][bk][bc4]           = bReg00;
    *(float4*)&Bs[0][bk][bc4 + 64]      = bReg01;
    *(float4*)&Bs[0][bk + 16][bc4]      = bReg10;
    *(float4*)&Bs[0][bk + 16][bc4 + 64] = bReg11;
    __syncthreads();
    float acc[2][4] = {};
    for (int it = 0; it < 16; it++) {
        int cur = it & 1;
        if (it + 1 < 16) {
            int k0 = (it + 1) * 32;
            if (tid < 128) {
                int gm = r0 + am;
                aReg = make_float4(0.f, 0.f, 0.f, 0.f);
                if (gm < M) aReg = *(const float4*)&A[(size_t)gm * D_ + k0 + aseg * 4];
            }
            bReg00 = *(const float4*)&W1c[(size_t)(k0 + bk) * DFF_ + bc4];
            bReg01 = *(const float4*)&W1c[(size_t)(k0 + bk) * DFF_ + bc4 + 64];
            bReg10 = *(const float4*)&W1c[(size_t)(k0 + bk + 16) * DFF_ + bc4];
            bReg11 = *(const float4*)&W1c[(size_t)(k0 + bk + 16) * DFF_ + bc4 + 64];
        }
        #pragma unroll
        for (int kk = 0; kk < 32; kk++) {
            float2 a2 = *(const float2*)&As[cur][kk][ty * 2];
            float4 b4 = *(const float4*)&Bs[cur][kk][tx * 4];
            acc[0][0] += a2.x * b4.x; acc[0][1] += a2.x * b4.y;
            acc[0][2] += a2.x * b4.z; acc[0][3] += a2.x * b4.w;
            acc[1][0] += a2.y * b4.x; acc[1][1] += a2.y * b4.y;
            acc[1][2] += a2.y * b4.z; acc[1][3] += a2.y * b4.w;
        }
        if (it + 1 < 16) {
            int nxt = 1 - cur;
            if (tid < 128) {
                As[nxt][aseg * 4 + 0][am] = aReg.x;
                As[nxt][aseg * 4 + 1][am] = aReg.y;
                As[nxt][aseg * 4 + 2][am] = aReg.z;
                As[nxt][aseg * 4 + 3][am] = aReg.w;
            }
            *(float4*)&Bs[nxt][bk][bc4]           = bReg00;
            *(float4*)&Bs[nxt][bk][bc4 + 64]      = bReg01;
            *(float4*)&Bs[nxt][bk + 16][bc4]      = bReg10;
            *(float4*)&Bs[nxt][bk + 16][bc4 + 64] = bReg11;
        }
        __syncthreads();
    }
    // bias + relu -> hs
    {
        float4 bv = *(const float4*)&b1[bx * 128 + tx * 4];
        #pragma unroll
        for (int i = 0; i < 2; i++) {
            float4 o;
            o.x = fmaxf(acc[i][0] + bv.x, 0.f);
            o.y = fmaxf(acc[i][1] + bv.y, 0.f);
            o.z = fmaxf(acc[i][2] + bv.z, 0.f);
            o.w = fmaxf(acc[i][3] + bv.w, 0.f);
            *(float4*)&hs[ty * 2 + i][tx * 4] = o;
        }
    }
    __syncthreads();
    // ---- phase 2: parts[bx][16 rows][512] = hs @ w2 chunk (hs via float4)
    int rh = tid >> 7, cg = tid & 127;       // 8 rows per half, col cg*4
    float acc2[8][4] = {};
    const float* W2c = w2 + (size_t)(bx * 128) * D_;
    for (int k = 0; k < 128; k += 4) {
        float4 w0 = *(const float4*)&W2c[(size_t)(k + 0) * D_ + cg * 4];
        float4 w1v = *(const float4*)&W2c[(size_t)(k + 1) * D_ + cg * 4];
        float4 w2v = *(const float4*)&W2c[(size_t)(k + 2) * D_ + cg * 4];
        float4 w3 = *(const float4*)&W2c[(size_t)(k + 3) * D_ + cg * 4];
        #pragma unroll
        for (int r = 0; r < 8; r++) {
            float4 hv = *(const float4*)&hs[rh * 8 + r][k];
            acc2[r][0] += hv.x * w0.x; acc2[r][1] += hv.x * w0.y;
            acc2[r][2] += hv.x * w0.z; acc2[r][3] += hv.x * w0.w;
            acc2[r][0] += hv.y * w1v.x; acc2[r][1] += hv.y * w1v.y;
            acc2[r][2] += hv.y * w1v.z; acc2[r][3] += hv.y * w1v.w;
            acc2[r][0] += hv.z * w2v.x; acc2[r][1] += hv.z * w2v.y;
            acc2[r][2] += hv.z * w2v.z; acc2[r][3] += hv.z * w2v.w;
            acc2[r][0] += hv.w * w3.x; acc2[r][1] += hv.w * w3.y;
            acc2[r][2] += hv.w * w3.z; acc2[r][3] += hv.w * w3.w;
        }
    }
    float* P = parts + (size_t)bx * XSZ;
    #pragma unroll
    for (int r = 0; r < 8; r++) {
        int gm = r0 + rh * 8 + r;
        if (gm < M) {
            float4 o;
            o.x = acc2[r][0]; o.y = acc2[r][1];
            o.z = acc2[r][2]; o.w = acc2[r][3];
            *(float4*)&P[(size_t)gm * D_ + cg * 4] = o;
        }
    }
}

// ---------------------------------------------------------------------------
__global__ void init_k(int* __restrict__ tokens, int* __restrict__ done,
                       float* __restrict__ cmask, const float* __restrict__ pm)
{
    int tid = threadIdx.x + blockIdx.x * 256;
    if (tid < B_ * TP1) tokens[tid] = ((tid % TP1) == 0) ? 1 : 0;
    if (tid < B_) done[tid] = 0;
    if (tid < B_ * SENC) cmask[tid] = pm[tid] * NEGV;
}

// ---------------------------------------------------------------------------
__global__ __launch_bounds__(256) void pe_k(float* __restrict__ pe)
{
    int p = blockIdx.x;
    for (int d = threadIdx.x; d < D_; d += 256) {
        float fd = (float)(2 * (d / 2)) / (float)D_;
        float ang = (float)p / powf(10000.f, fd);
        pe[(size_t)p * D_ + d] = (d & 1) ? cosf(ang) : sinf(ang);
    }
}

// ---------------------------------------------------------------------------
// Fused embed + (for the p==t block) argmax of previous step's logits.
// ---------------------------------------------------------------------------
__global__ __launch_bounds__(256) void embed_k(
    const float* __restrict__ embed, int* __restrict__ tokens,
    float* __restrict__ x, const float* __restrict__ pe,
    const float* __restrict__ cand_v, const int* __restrict__ cand_i,
    int* __restrict__ done, int t)
{
    int p = blockIdx.x;
    int b = blockIdx.y;
    int tid = threadIdx.x;
    __shared__ float sv[128];
    __shared__ int si[128];
    __shared__ int stok;
    if (p == t && t > 0) {
        if (tid < 128) {
            float val = -1e30f; int idx = 0x7fffffff;
            if (tid < 125) {
                val = cand_v[(size_t)b * 125 + tid];
                idx = cand_i[(size_t)b * 125 + tid];
            }
            sv[tid] = val; si[tid] = idx;
        }
        __syncthreads();
        for (int s = 64; s; s >>= 1) {
            if (tid < s) {
                float ov = sv[tid + s]; int oi = si[tid + s];
                if (ov > sv[tid] || (ov == sv[tid] && oi < si[tid])) {
                    sv[tid] = ov; si[tid] = oi;
                }
            }
            __syncthreads();
        }
        if (tid == 0) {
            int best = si[0];
            int dn = done[b] | (best == 2 ? 1 : 0);
            done[b] = dn;
            int tk = dn ? 0 : best;
            tokens[b * TP1 + t] = tk;
            stok = tk;
        }
        __syncthreads();
    }
    int tok = (p == t && t > 0) ? stok : tokens[b * TP1 + p];
    const float* e = embed + (size_t)tok * D_;
    const float* pr = pe + (size_t)p * D_;
    float* xr = x + ((size_t)p * B_ + b) * D_;
    int c0 = tid * 2;
    float2 ev = *(const float2*)&e[c0];
    float2 pv = *(const float2*)&pr[c0];
    float2 o;
    o.x = ev.x * SQRTD + pv.x;
    o.y = ev.y * SQRTD + pv.y;
    *(float2*)&xr[c0] = o;
}

// ---------------------------------------------------------------------------
__device__ __forceinline__ float block_sum(float s) {
    __shared__ float red[4];
    #pragma unroll
    for (int off = 32; off; off >>= 1) s += __shfl_xor(s, off);
    if ((threadIdx.x & 63) == 0) red[threadIdx.x >> 6] = s;
    __syncthreads();
    float tot = red[0] + red[1] + red[2] + red[3];
    __syncthreads();
    return tot;
}

__device__ __forceinline__ float4 block_sum4(float4 s) {
    __shared__ __align__(16) float red4[4][4];
    #pragma unroll
    for (int off = 32; off; off >>= 1) {
        s.x += __shfl_xor(s.x, off);
        s.y += __shfl_xor(s.y, off);
        s.z += __shfl_xor(s.z, off);
        s.w += __shfl_xor(s.w, off);
    }
    if ((threadIdx.x & 63) == 0) *(float4*)red4[threadIdx.x >> 6] = s;
    __syncthreads();
    float4 t;
    t.x = red4[0][0] + red4[1][0] + red4[2][0] + red4[3][0];
    t.y = red4[0][1] + red4[1][1] + red4[2][1] + red4[3][1];
    t.z = red4[0][2] + red4[1][2] + red4[2][2] + red4[3][2];
    t.w = red4[0][3] + red4[1][3] + red4[2][3] + red4[3][3];
    __syncthreads();
    return t;
}

// ---------------------------------------------------------------------------
// MEGA: self-attn + wo + LN + cross(q-proj, attn, cwo) + LN. G=4 rows of the
// SAME batch per block. Row-major float2 weight loops (wave-coalesced).
// ---------------------------------------------------------------------------
__global__ __launch_bounds__(256) void attn_mega_k(
    const float* __restrict__ q, const float* __restrict__ kT,
    const float* __restrict__ v, const float* __restrict__ wo,
    const float* __restrict__ KcT, const float* __restrict__ Vc,
    const float* __restrict__ cmask, const float* __restrict__ cwq,
    const float* __restrict__ cwo, float* __restrict__ x,
    const float* __restrict__ lg, const float* __restrict__ lb, int P)
{
    int b = blockIdx.x;
    int p0 = blockIdx.y * 4;
    int tid = threadIdx.x;
    int c0 = tid * 2;
    __shared__ float xs[4][D_];
    __shared__ float arow[4][D_];
    __shared__ float scs[4][H_][SENC + 4];
    __shared__ float inv[4][H_];
    #pragma unroll
    for (int g = 0; g < 4; g++) {
        float2 qv = make_float2(0.f, 0.f);
        if (p0 + g < P)
            qv = *(const float2*)&q[((size_t)(p0 + g) * B_ + b) * D_ + c0];
        *(float2*)&arow[g][c0] = qv;
    }
    __syncthreads();
    {
        int h = tid >> 5, kp = tid & 31;
        float a0 = 0.f, a1 = 0.f, a2 = 0.f, a3 = 0.f;
        if (kp < P) {
            const float* kb = kT + ((size_t)(b * 8 + h) * 64) * TP1 + kp;
            #pragma unroll 8
            for (int d = 0; d < 64; d++) {
                float kv = kb[(size_t)d * TP1];
                a0 += arow[0][h * 64 + d] * kv;
                a1 += arow[1][h * 64 + d] * kv;
                a2 += arow[2][h * 64 + d] * kv;
                a3 += arow[3][h * 64 + d] * kv;
            }
        }
        scs[0][h][kp] = a0 * 0.125f;
        scs[1][h][kp] = a1 * 0.125f;
        scs[2][h][kp] = a2 * 0.125f;
        scs[3][h][kp] = a3 * 0.125f;
    }
    __syncthreads();
    {
        int gh = tid >> 3, lane8 = tid & 7;
        int g = gh >> 3, h = gh & 7;
        float mx = -1e30f;
        for (int j = lane8; j < P; j += 8) mx = fmaxf(mx, scs[g][h][j]);
        mx = fmaxf(mx, __shfl_xor(mx, 1));
        mx = fmaxf(mx, __shfl_xor(mx, 2));
        mx = fmaxf(mx, __shfl_xor(mx, 4));
        float sum = 0.f;
        for (int j = lane8; j < P; j += 8) {
            float e = expf(scs[g][h][j] - mx);
            scs[g][h][j] = e;
            sum += e;
        }
        sum += __shfl_xor(sum, 1);
        sum += __shfl_xor(sum, 2);
        sum += __shfl_xor(sum, 4);
        if (lane8 == 0) inv[g][h] = 1.f / sum;
    }
    __syncthreads();
    {
        int h = tid >> 5;
        float o0[4] = {0.f, 0.f, 0.f, 0.f}, o1[4] = {0.f, 0.f, 0.f, 0.f};
        for (int j = 0; j < P; j++) {
            float2 vv = *(const float2*)&v[((size_t)j * B_ + b) * D_ + c0];
            #pragma unroll
            for (int g = 0; g < 4; g++) {
                float w = scs[g][h][j];
                o0[g] += w * vv.x; o1[g] += w * vv.y;
            }
        }
        #pragma unroll
        for (int g = 0; g < 4; g++) {
            arow[g][c0]     = o0[g] * inv[g][h];
            arow[g][c0 + 1] = o1[g] * inv[g][h];
        }
    }
    __syncthreads();
    {
        float v0[4], v1[4];
        #pragma unroll
        for (int g = 0; g < 4; g++) {
            float2 xv = make_float2(0.f, 0.f);
            if (p0 + g < P)
                xv = *(const float2*)&x[((size_t)(p0 + g) * B_ + b) * D_ + c0];
            v0[g] = xv.x; v1[g] = xv.y;
        }
        #pragma unroll 8
        for (int k = 0; k < D_; k++) {
            float2 wv = *(const float2*)&wo[(size_t)k * D_ + c0];
            #pragma unroll
            for (int g = 0; g < 4; g++) {
                float a = arow[g][k];
                v0[g] += a * wv.x; v1[g] += a * wv.y;
            }
        }
        float4 s1 = make_float4(v0[0] + v1[0], v0[1] + v1[1],
                                v0[2] + v1[2], v0[3] + v1[3]);
        float4 m4 = block_sum4(s1);
        float mean[4] = {m4.x * (1.f / 512.f), m4.y * (1.f / 512.f),
                         m4.z * (1.f / 512.f), m4.w * (1.f / 512.f)};
        float d0[4], d1[4];
        #pragma unroll
        for (int g = 0; g < 4; g++) {
            d0[g] = v0[g] - mean[g]; d1[g] = v1[g] - mean[g];
        }
        float4 s2 = make_float4(d0[0] * d0[0] + d1[0] * d1[0],
                                d0[1] * d0[1] + d1[1] * d1[1],
                                d0[2] * d0[2] + d1[2] * d1[2],
                                d0[3] * d0[3] + d1[3] * d1[3]);
        float4 w4 = block_sum4(s2);
        float var[4] = {w4.x * (1.f / 512.f), w4.y * (1.f / 512.f),
                        w4.z * (1.f / 512.f), w4.w * (1.f / 512.f)};
        float g0 = lg[c0], g1 = lg[c0 + 1];
        float bb0 = lb[c0], bb1 = lb[c0 + 1];
        #pragma unroll
        for (int g = 0; g < 4; g++) {
            float rs = rsqrtf(var[g] + EPSV);
            xs[g][c0]     = d0[g] * rs * g0 + bb0;
            xs[g][c0 + 1] = d1[g] * rs * g1 + bb1;
        }
    }
    __syncthreads();
    {
        float q0[4] = {0.f, 0.f, 0.f, 0.f}, q1[4] = {0.f, 0.f, 0.f, 0.f};
        #pragma unroll 8
        for (int k = 0; k < D_; k++) {
            float2 wv = *(const float2*)&cwq[(size_t)k * D_ + c0];
            #pragma unroll
            for (int g = 0; g < 4; g++) {
                float a = xs[g][k];
                q0[g] += a * wv.x; q1[g] += a * wv.y;
            }
        }
        #pragma unroll
        for (int g = 0; g < 4; g++) {
            arow[g][c0] = q0[g]; arow[g][c0 + 1] = q1[g];
        }
    }
    __syncthreads();
    #pragma unroll
    for (int i = 0; i < 4; i++) {
        int idx = tid + i * 256;
        int h = idx >> 7, s = idx & 127;
        const float* kb = KcT + ((size_t)(b * 512 + h * 64)) * SENC + s;
        float a0 = 0.f, a1 = 0.f, a2 = 0.f, a3 = 0.f;
        #pragma unroll 8
        for (int d = 0; d < 64; d++) {
            float kc = kb[(size_t)d * SENC];
            a0 += arow[0][h * 64 + d] * kc;
            a1 += arow[1][h * 64 + d] * kc;
            a2 += arow[2][h * 64 + d] * kc;
            a3 += arow[3][h * 64 + d] * kc;
        }
        float cm = cmask[b * SENC + s];
        scs[0][h][s] = a0 * 0.125f + cm;
        scs[1][h][s] = a1 * 0.125f + cm;
        scs[2][h][s] = a2 * 0.125f + cm;
        scs[3][h][s] = a3 * 0.125f + cm;
    }
    __syncthreads();
    {
        int gh = tid >> 3, lane8 = tid & 7;
        int g = gh >> 3, h = gh & 7;
        float mx = -1e30f;
        for (int s = lane8; s < SENC; s += 8) mx = fmaxf(mx, scs[g][h][s]);
        mx = fmaxf(mx, __shfl_xor(mx, 1));
        mx = fmaxf(mx, __shfl_xor(mx, 2));
        mx = fmaxf(mx, __shfl_xor(mx, 4));
        float sum = 0.f;
        for (int s = lane8; s < SENC; s += 8) {
            float e = expf(scs[g][h][s] - mx);
            scs[g][h][s] = e;
            sum += e;
        }
        sum += __shfl_xor(sum, 1);
        sum += __shfl_xor(sum, 2);
        sum += __shfl_xor(sum, 4);
        if (lane8 == 0) inv[g][h] = 1.f / sum;
    }
    __syncthreads();
    {
        int h = tid >> 5;
        float o0[4] = {0.f, 0.f, 0.f, 0.f}, o1[4] = {0.f, 0.f, 0.f, 0.f};
        for (int s = 0; s < SENC; s++) {
            float2 vv = *(const float2*)&Vc[((size_t)b * SENC + s) * D_ + c0];
            #pragma unroll
            for (int g = 0; g < 4; g++) {
                float w = scs[g][h][s];
                o0[g] += w * vv.x; o1[g] += w * vv.y;
            }
        }
        #pragma unroll
        for (int g = 0; g < 4; g++) {
            arow[g][c0]     = o0[g] * inv[g][h];
            arow[g][c0 + 1] = o1[g] * inv[g][h];
        }
    }
    __syncthreads();
    {
        float v0[4], v1[4];
        #pragma unroll
        for (int g = 0; g < 4; g++) {
            v0[g] = xs[g][c0]; v1[g] = xs[g][c0 + 1];
        }
        #pragma unroll 8
        for (int k = 0; k < D_; k++) {
            float2 wv = *(const float2*)&cwo[(size_t)k * D_ + c0];
            #pragma unroll
            for (int g = 0; g < 4; g++) {
                float a = arow[g][k];
                v0[g] += a * wv.x; v1[g] += a * wv.y;
            }
        }
        float4 s1 = make_float4(v0[0] + v1[0], v0[1] + v1[1],
                                v0[2] + v1[2], v0[3] + v1[3]);
        float4 m4 = block_sum4(s1);
        float mean[4] = {m4.x * (1.f / 512.f), m4.y * (1.f / 512.f),
                         m4.z * (1.f / 512.f), m4.w * (1.f / 512.f)};
        float d0[4], d1[4];
        #pragma unroll
        for (int g = 0; g < 4; g++) {
            d0[g] = v0[g] - mean[g]; d1[g] = v1[g] - mean[g];
        }
        float4 s2 = make_float4(d0[0] * d0[0] + d1[0] * d1[0],
                                d0[1] * d0[1] + d1[1] * d1[1],
                                d0[2] * d0[2] + d1[2] * d1[2],
                                d0[3] * d0[3] + d1[3] * d1[3]);
        float4 w4 = block_sum4(s2);
        float var[4] = {w4.x * (1.f / 512.f), w4.y * (1.f / 512.f),
                        w4.z * (1.f / 512.f), w4.w * (1.f / 512.f)};
        float g0 = lg[D_ + c0], g1 = lg[D_ + c0 + 1];
        float bb0 = lb[D_ + c0], bb1 = lb[D_ + c0 + 1];
        #pragma unroll
        for (int g = 0; g < 4; g++) {
            if (p0 + g < P) {
                float rs = rsqrtf(var[g] + EPSV);
                float* xr = x + ((size_t)(p0 + g) * B_ + b) * D_;
                xr[c0]     = d0[g] * rs * g0 + bb0;
                xr[c0 + 1] = d1[g] * rs * g1 + bb1;
            }
        }
    }
}

// ---------------------------------------------------------------------------
// x = LN(x + sum_parts (+ bias)) * g + b. One block per row.
// ---------------------------------------------------------------------------
__global__ __launch_bounds__(256) void ln_red_k(
    float* __restrict__ x, const float* __restrict__ parts, size_t pstride,
    int nparts, const float* __restrict__ bias,
    const float* __restrict__ gam, const float* __restrict__ bet)
{
    int r = blockIdx.x;
    float* xr = x + (size_t)r * D_;
    int tid = threadIdx.x;
    float v0 = xr[tid];
    float v1 = xr[tid + 256];
    for (int s = 0; s < nparts; s++) {
        const float* pr = parts + (size_t)s * pstride + (size_t)r * D_;
        v0 += pr[tid];
        v1 += pr[tid + 256];
    }
    if (bias) { v0 += bias[tid]; v1 += bias[tid + 256]; }
    float mean = block_sum(v0 + v1) * (1.f / 512.f);
    float d0 = v0 - mean, d1 = v1 - mean;
    float var = block_sum(d0 * d0 + d1 * d1) * (1.f / 512.f);
    float rs = rsqrtf(var + EPSV);
    xr[tid]       = d0 * rs * gam[tid] + bet[tid];
    xr[tid + 256] = d1 * rs * gam[tid + 256] + bet[tid + 256];
}

// ---------------------------------------------------------------------------
// logits -> per-block argmax candidates. LDS-staged xs (best measured),
// xs reads as float4 (4-k unroll; per-b adds stay k-ascending -> bitwise
// identical to the scalar version).
// ---------------------------------------------------------------------------
__global__ __launch_bounds__(256) void logits_k(
    const float* __restrict__ x, const float* __restrict__ fcw,
    const float* __restrict__ fcb, float* __restrict__ cand_v,
    int* __restrict__ cand_i, int t)
{
    __shared__ __align__(16) float xs[B_][D_];
    __shared__ float red[4][64][B_];
    int tid = threadIdx.x;
    for (int i = tid; i < B_ * D_; i += 256) {
        int b = i >> 9, d = i & 511;
        xs[b][d] = x[((size_t)t * B_ + b) * D_ + d];
    }
    __syncthreads();
    int lane = tid & 63, ks = tid >> 6;
    int col = blockIdx.x * 64 + lane;
    float acc[B_] = {};
    int kb = ks * 128;
    for (int k = kb; k < kb + 128; k += 4) {
        float w0 = fcw[(size_t)(k + 0) * V_ + col];
        float w1 = fcw[(size_t)(k + 1) * V_ + col];
        float w2 = fcw[(size_t)(k + 2) * V_ + col];
        float w3 = fcw[(size_t)(k + 3) * V_ + col];
        #pragma unroll
        for (int b = 0; b < B_; b++) {
            float4 xv = *(const float4*)&xs[b][k];
            acc[b] += xv.x * w0;
            acc[b] += xv.y * w1;
            acc[b] += xv.z * w2;
            acc[b] += xv.w * w3;
        }
    }
    #pragma unroll
    for (int b = 0; b < B_; b++) red[ks][lane][b] = acc[b];
    __syncthreads();
    if (ks == 0) {
        float bias = fcb[col];
        #pragma unroll
        for (int b = 0; b < B_; b++) {
            float val = red[0][lane][b] + red[1][lane][b]
                      + red[2][lane][b] + red[3][lane][b] + bias;
            int idx = col;
            #pragma unroll
            for (int off = 32; off; off >>= 1) {
                float ov = __shfl_down(val, off);
                int oi = __shfl_down(idx, off);
                if (ov > val || (ov == val && oi < idx)) { val = ov; idx = oi; }
            }
            if (lane == 0) {
                cand_v[(size_t)b * 125 + blockIdx.x] = val;
                cand_i[(size_t)b * 125 + blockIdx.x] = idx;
            }
        }
    }
}

// ---------------------------------------------------------------------------
__global__ __launch_bounds__(128) void writeout_k(
    const int* __restrict__ tokens, const float* __restrict__ cand_v,
    const int* __restrict__ cand_i, const int* __restrict__ done,
    int* __restrict__ out)
{
    int b = blockIdx.x;
    int tid = threadIdx.x;
    __shared__ float sv[128];
    __shared__ int si[128];
    __shared__ int stok;
    float val = -1e30f; int idx = 0x7fffffff;
    if (tid < 125) {
        val = cand_v[(size_t)b * 125 + tid];
        idx = cand_i[(size_t)b * 125 + tid];
    }
    sv[tid] = val; si[tid] = idx;
    __syncthreads();
    for (int s = 64; s; s >>= 1) {
        if (tid < s) {
            float ov = sv[tid + s]; int oi = si[tid + s];
            if (ov > sv[tid] || (ov == sv[tid] && oi < si[tid])) {
                sv[tid] = ov; si[tid] = oi;
            }
        }
        __syncthreads();
    }
    if (tid == 0) {
        int best = si[0];
        int dn = done[b] | (best == 2 ? 1 : 0);
        stok = dn ? 0 : best;
    }
    __syncthreads();
    if (tid < T_)
        out[b * T_ + tid] = (tid == T_ - 1) ? stok : tokens[b * TP1 + tid + 1];
}

// ---------------------------------------------------------------------------
extern "C" void kernel_launch(void* const* d_in, const int* in_sizes, int n_in,
                              void* d_out, int out_size, void* d_ws, size_t ws_size,
                              hipStream_t stream)
{
    const float* enc   = (const float*)d_in[1];
    const float* pm    = (const float*)d_in[2];
    const float* embed = (const float*)d_in[3];
    const float* wq    = (const float*)d_in[4];
    const float* wk    = (const float*)d_in[5];
    const float* wv    = (const float*)d_in[6];
    const float* wo    = (const float*)d_in[7];
    const float* cwq   = (const float*)d_in[8];
    const float* cwk   = (const float*)d_in[9];
    const float* cwv   = (const float*)d_in[10];
    const float* cwo   = (const float*)d_in[11];
    const float* w1    = (const float*)d_in[12];
    const float* b1    = (const float*)d_in[13];
    const float* w2    = (const float*)d_in[14];
    const float* b2    = (const float*)d_in[15];
    const float* ln_g  = (const float*)d_in[16];
    const float* ln_b  = (const float*)d_in[17];
    const float* fcw   = (const float*)d_in[18];
    const float* fcb   = (const float*)d_in[19];

    float* ws = (float*)d_ws;
    size_t off = 0;
    float* x     = ws + off; off += XSZ;
    float* qkv   = ws + off; off += 3 * XSZ;      // q | kT | v
    float* parts = ws + off; off += NCH * XSZ;    // 16 dff-chunk partials
    float* ffnh  = parts + 4 * XSZ;               // alias (fallback only)
    float* cand_v= ws + off; off += (size_t)B_ * 125;
    float* KcT   = ws + off; off += (size_t)L_ * B_ * SENC * D_;
    float* Vc    = ws + off; off += (size_t)L_ * B_ * SENC * D_;
    float* cmask = ws + off; off += (size_t)B_ * SENC;
    float* pe    = ws + off; off += (size_t)TP1 * D_;
    int* cand_i  = (int*)(ws + off); off += (size_t)B_ * 125;
    int* tokens  = (int*)(ws + off); off += (B_ * TP1 + 63) & ~63;
    int* done    = (int*)(ws + off); off += 64;
    int fused = (ws_size >= off * sizeof(float)) ? 1 : 0;

    init_k<<<8, 256, 0, stream>>>(tokens, done, cmask, pm);
    pe_k<<<TP1, 256, 0, stream>>>(pe);

    const size_t KVL = (size_t)B_ * SENC * D_;
    for (int l = 0; l < L_; l++) {
        gemm32_k<<<dim3(8, (B_ * SENC) / 32), 256, 0, stream>>>(
            enc, cwk + (size_t)l * D_ * D_, nullptr, KcT + l * KVL,
            B_ * SENC, D_, D_, D_, 0, 0, 1);
        gemm32_k<<<dim3(8, (B_ * SENC) / 32), 256, 0, stream>>>(
            enc, cwv + (size_t)l * D_ * D_, nullptr, Vc + l * KVL,
            B_ * SENC, D_, D_, D_, 0, 0, 0);
    }

    for (int t = 0; t < T_; t++) {
        int P = t + 1;
        int M = P * B_;
        int mt = (M + 31) / 32;

        embed_k<<<dim3(P, B_), 256, 0, stream>>>(
            embed, tokens, x, pe, cand_v, cand_i, done, t);

        for (int l = 0; l < L_; l++) {
            const size_t lw = (size_t)l * D_ * D_;
            gemm_qkv_k<<<dim3(24, mt), 256, 0, stream>>>(
                x, wq + lw, wk + lw, wv + lw, qkv, M);
            attn_mega_k<<<dim3(B_, (P + 3) / 4), 256, 0, stream>>>(
                qkv, qkv + XSZ, qkv + 2 * XSZ, wo + lw,
                KcT + l * KVL, Vc + l * KVL, cmask, cwq + lw, cwo + lw, x,
                ln_g + (size_t)(l * 3 + 0) * D_, ln_b + (size_t)(l * 3 + 0) * D_, P);
            if (fused) {
                ffn_fused_k<<<dim3(NCH, (M + 15) / 16), 256, 0, stream>>>(
                    x, w1 + (size_t)l * D_ * DFF_, b1 + (size_t)l * DFF_,
                    w2 + (size_t)l * DFF_ * D_, parts, M);
                ln_red_k<<<M, 256, 0, stream>>>(x, parts, XSZ, NCH,
                    b2 + (size_t)l * D_,
                    ln_g + (size_t)(l * 3 + 2) * D_, ln_b + (size_t)(l * 3 + 2) * D_);
            } else {
                gemm32_k<<<dim3(32, mt), 256, 0, stream>>>(
                    x, w1 + (size_t)l * D_ * DFF_, b1 + (size_t)l * DFF_, ffnh,
                    M, DFF_, D_, D_, 0, 1, 0);
                gemm32_k<<<dim3(8, mt, 4), 256, 0, stream>>>(
                    ffnh, w2 + (size_t)l * DFF_ * D_, nullptr, parts,
                    M, D_, DFF_, 512, XSZ, 0, 0);
                ln_red_k<<<M, 256, 0, stream>>>(x, parts, XSZ, 4,
                    b2 + (size_t)l * D_,
                    ln_g + (size_t)(l * 3 + 2) * D_, ln_b + (size_t)(l * 3 + 2) * D_);
            }
        }

        logits_k<<<V_ / 64, 256, 0, stream>>>(x, fcw, fcb, cand_v, cand_i, t);
    }

    writeout_k<<<B_, 128, 0, stream>>>(tokens, cand_v, cand_i, done, (int*)d_out);
}